// Round 3
// baseline (1680.799 us; speedup 1.0000x reference)
//
#include <hip/hip_runtime.h>
#include <math.h>

#define HH 16
#define DD 64
#define TS 2048
#define EE 1024
#define BB 4
#define MS 12.0f

typedef __attribute__((ext_vector_type(8))) __bf16 bf16x8;
typedef __attribute__((ext_vector_type(8))) _Float16 f16x8;
typedef __attribute__((ext_vector_type(4))) float f32x4;

// LDS-only barrier: sync LDS without draining vmcnt (global loads/stores stay in flight).
// Single asm block so no memory op can be scheduled between the wait and the barrier.
#define LBAR() asm volatile("s_waitcnt lgkmcnt(0)\n\ts_barrier" ::: "memory")

__device__ __forceinline__ f32x4 mm3(bf16x8 ah, bf16x8 al, bf16x8 bh, bf16x8 bl, f32x4 c) {
    c = __builtin_amdgcn_mfma_f32_16x16x32_bf16(ah, bh, c, 0, 0, 0);
    c = __builtin_amdgcn_mfma_f32_16x16x32_bf16(ah, bl, c, 0, 0, 0);
    c = __builtin_amdgcn_mfma_f32_16x16x32_bf16(al, bh, c, 0, 0, 0);
    return c;
}

__device__ __forceinline__ void gll16(const void* g, void* l) {
    __builtin_amdgcn_global_load_lds(
        (const __attribute__((address_space(1))) unsigned int*)g,
        (__attribute__((address_space(3))) unsigned int*)l, 16, 0, 0);
}

__device__ __forceinline__ unsigned pk2(float p) {
    __bf16 h = (__bf16)p;
    __bf16 l = (__bf16)(p - (float)h);
    return ((unsigned)__builtin_bit_cast(unsigned short, h) << 16) |
            (unsigned)__builtin_bit_cast(unsigned short, l);
}
__device__ __forceinline__ float upk_hi(unsigned u) { return __builtin_bit_cast(float, u & 0xffff0000u); }
__device__ __forceinline__ float upk_lo(unsigned u) { return __builtin_bit_cast(float, u << 16); }

__device__ __forceinline__ bf16x8 sel_frag(uint4 a, uint4 b, unsigned s) {
    uint4 r;
    r.x = __builtin_amdgcn_perm(a.y, a.x, s);
    r.y = __builtin_amdgcn_perm(a.w, a.z, s);
    r.z = __builtin_amdgcn_perm(b.y, b.x, s);
    r.w = __builtin_amdgcn_perm(b.w, b.z, s);
    return __builtin_bit_cast(bf16x8, r);
}

__device__ __forceinline__ void split8(const float* __restrict__ src,
    __bf16* __restrict__ hi, __bf16* __restrict__ lo, size_t i)
{
    float4 a = *(const float4*)(src + i);
    float4 b = *(const float4*)(src + i + 4);
    float v[8] = {a.x, a.y, a.z, a.w, b.x, b.y, b.z, b.w};
    bf16x8 h, l;
    #pragma unroll
    for (int j = 0; j < 8; ++j) {
        __bf16 x = (__bf16)v[j];
        h[j] = x;
        l[j] = (__bf16)(v[j] - (float)x);
    }
    *(bf16x8*)(hi + i) = h;
    *(bf16x8*)(lo + i) = l;
}

// ---------------- fp32 -> bf16 hi/lo split: q/k/v batched (y selects tensor) --------
__global__ __launch_bounds__(256) void splitX(
    const float* __restrict__ q, const float* __restrict__ k, const float* __restrict__ v,
    __bf16* __restrict__ qh, __bf16* __restrict__ ql,
    __bf16* __restrict__ kh, __bf16* __restrict__ kl,
    __bf16* __restrict__ vh, __bf16* __restrict__ vl)
{
    const int z = blockIdx.y;
    const float* src = z == 0 ? q : z == 1 ? k : v;
    __bf16* hi = z == 0 ? qh : z == 1 ? kh : vh;
    __bf16* lo = z == 0 ? ql : z == 1 ? kl : vl;
    size_t i = ((size_t)blockIdx.x * 256 + threadIdx.x) * 8;
    split8(src, hi, lo, i);
}

// ---------------- weights batched (y selects tensor) ----------------
__global__ __launch_bounds__(256) void splitW(
    const float* __restrict__ wq, const float* __restrict__ wk,
    const float* __restrict__ wv, const float* __restrict__ wo,
    __bf16* __restrict__ qh, __bf16* __restrict__ ql,
    __bf16* __restrict__ kh, __bf16* __restrict__ kl,
    __bf16* __restrict__ vh, __bf16* __restrict__ vl,
    __bf16* __restrict__ oh, __bf16* __restrict__ ol)
{
    const int z = blockIdx.y;
    const float* src = z == 0 ? wq : z == 1 ? wk : z == 2 ? wv : wo;
    __bf16* hi = z == 0 ? qh : z == 1 ? kh : z == 2 ? vh : oh;
    __bf16* lo = z == 0 ? ql : z == 1 ? kl : z == 2 ? vl : ol;
    size_t i = ((size_t)blockIdx.x * 256 + threadIdx.x) * 8;
    split8(src, hi, lo, i);
}

// ---------------- 3-term split-bf16 MFMA GEMM: C[M,N] = A[M,K]*B[N,K]^T ----------------
// OMODE 0: f32 C[M,N]
template<int OMODE>
__global__ __launch_bounds__(256) void gemm3(
    const __bf16* __restrict__ Ah, const __bf16* __restrict__ Al,
    const __bf16* __restrict__ Bh, const __bf16* __restrict__ Bl,
    float* __restrict__ Cf, __bf16* __restrict__ Ch, __bf16* __restrict__ Cl,
    int M, int N, int K)
{
    __shared__ __bf16 sA[2][128 * 32];
    __shared__ __bf16 sB[2][128 * 32];
    const int tid = threadIdx.x, wave = tid >> 6, lane = tid & 63;
    const int quad = lane >> 4, l15 = lane & 15;
    const int m0 = blockIdx.y * 128, n0 = blockIdx.x * 128;
    const int wm = (wave >> 1) * 64, wn = (wave & 1) * 64;
    const int srow = lane >> 2, scol = (lane & 3) * 8;

    f32x4 acc[4][4];
    #pragma unroll
    for (int i = 0; i < 4; ++i)
        #pragma unroll
        for (int j = 0; j < 4; ++j)
            acc[i][j] = (f32x4){0.f, 0.f, 0.f, 0.f};

    for (int k0 = 0; k0 < K; k0 += 32) {
        __syncthreads();
        #pragma unroll
        for (int i = 0; i < 2; ++i) {
            int c = wave * 2 + i;
            size_t ga = (size_t)(m0 + c * 16 + srow) * K + k0 + scol;
            size_t gb = (size_t)(n0 + c * 16 + srow) * K + k0 + scol;
            gll16(Ah + ga, &sA[0][c * 512]);
            gll16(Al + ga, &sA[1][c * 512]);
            gll16(Bh + gb, &sB[0][c * 512]);
            gll16(Bl + gb, &sB[1][c * 512]);
        }
        __syncthreads();
        bf16x8 fAh[4], fAl[4], fBh[4], fBl[4];
        #pragma unroll
        for (int mb = 0; mb < 4; ++mb) {
            int r = (wm + mb * 16 + l15) * 32 + quad * 8;
            fAh[mb] = *(const bf16x8*)&sA[0][r];
            fAl[mb] = *(const bf16x8*)&sA[1][r];
        }
        #pragma unroll
        for (int nb = 0; nb < 4; ++nb) {
            int r = (wn + nb * 16 + l15) * 32 + quad * 8;
            fBh[nb] = *(const bf16x8*)&sB[0][r];
            fBl[nb] = *(const bf16x8*)&sB[1][r];
        }
        #pragma unroll
        for (int mb = 0; mb < 4; ++mb)
            #pragma unroll
            for (int nb = 0; nb < 4; ++nb)
                acc[mb][nb] = mm3(fAh[mb], fAl[mb], fBh[nb], fBl[nb], acc[mb][nb]);
    }

    #pragma unroll
    for (int mb = 0; mb < 4; ++mb)
        #pragma unroll
        for (int nb = 0; nb < 4; ++nb)
            #pragma unroll
            for (int r = 0; r < 4; ++r) {
                int m = m0 + wm + mb * 16 + quad * 4 + r;
                int n = n0 + wn + nb * 16 + l15;
                float v = acc[mb][nb][r];
                Cf[(size_t)m * N + n] = v;
            }
}

// ---------------- batched QKV projection GEMM (z selects tensor) ----------------
// z=0: Q -> [B,H,T,D] hi/lo;  z=1: K -> [B,H,T,D];  z=2: V -> [B,H,D,T] (transposed)
__global__ __launch_bounds__(256) void gemmQKV(
    const __bf16* __restrict__ xqh, const __bf16* __restrict__ xql,
    const __bf16* __restrict__ xkh, const __bf16* __restrict__ xkl,
    const __bf16* __restrict__ xvh, const __bf16* __restrict__ xvl,
    const __bf16* __restrict__ wqh, const __bf16* __restrict__ wql,
    const __bf16* __restrict__ wkh, const __bf16* __restrict__ wkl,
    const __bf16* __restrict__ wvh, const __bf16* __restrict__ wvl,
    __bf16* __restrict__ Qh, __bf16* __restrict__ Ql,
    __bf16* __restrict__ Kh, __bf16* __restrict__ Kl,
    __bf16* __restrict__ Vh, __bf16* __restrict__ Vl)
{
    const int z = blockIdx.z;
    const __bf16* Ah = z == 0 ? xqh : z == 1 ? xkh : xvh;
    const __bf16* Al = z == 0 ? xql : z == 1 ? xkl : xvl;
    const __bf16* Bh = z == 0 ? wqh : z == 1 ? wkh : wvh;
    const __bf16* Bl = z == 0 ? wql : z == 1 ? wkl : wvl;
    __bf16* Ch = z == 0 ? Qh : z == 1 ? Kh : Vh;
    __bf16* Cl = z == 0 ? Ql : z == 1 ? Kl : Vl;
    const int K = EE, N = HH * DD;

    __shared__ __bf16 sA[2][128 * 32];
    __shared__ __bf16 sB[2][128 * 32];
    const int tid = threadIdx.x, wave = tid >> 6, lane = tid & 63;
    const int quad = lane >> 4, l15 = lane & 15;
    const int m0 = blockIdx.y * 128, n0 = blockIdx.x * 128;
    const int wm = (wave >> 1) * 64, wn = (wave & 1) * 64;
    const int srow = lane >> 2, scol = (lane & 3) * 8;

    f32x4 acc[4][4];
    #pragma unroll
    for (int i = 0; i < 4; ++i)
        #pragma unroll
        for (int j = 0; j < 4; ++j)
            acc[i][j] = (f32x4){0.f, 0.f, 0.f, 0.f};

    for (int k0 = 0; k0 < K; k0 += 32) {
        __syncthreads();
        #pragma unroll
        for (int i = 0; i < 2; ++i) {
            int c = wave * 2 + i;
            size_t ga = (size_t)(m0 + c * 16 + srow) * K + k0 + scol;
            size_t gb = (size_t)(n0 + c * 16 + srow) * K + k0 + scol;
            gll16(Ah + ga, &sA[0][c * 512]);
            gll16(Al + ga, &sA[1][c * 512]);
            gll16(Bh + gb, &sB[0][c * 512]);
            gll16(Bl + gb, &sB[1][c * 512]);
        }
        __syncthreads();
        bf16x8 fAh[4], fAl[4], fBh[4], fBl[4];
        #pragma unroll
        for (int mb = 0; mb < 4; ++mb) {
            int r = (wm + mb * 16 + l15) * 32 + quad * 8;
            fAh[mb] = *(const bf16x8*)&sA[0][r];
            fAl[mb] = *(const bf16x8*)&sA[1][r];
        }
        #pragma unroll
        for (int nb = 0; nb < 4; ++nb) {
            int r = (wn + nb * 16 + l15) * 32 + quad * 8;
            fBh[nb] = *(const bf16x8*)&sB[0][r];
            fBl[nb] = *(const bf16x8*)&sB[1][r];
        }
        #pragma unroll
        for (int mb = 0; mb < 4; ++mb)
            #pragma unroll
            for (int nb = 0; nb < 4; ++nb)
                acc[mb][nb] = mm3(fAh[mb], fAl[mb], fBh[nb], fBl[nb], acc[mb][nb]);
    }

    #pragma unroll
    for (int mb = 0; mb < 4; ++mb)
        #pragma unroll
        for (int nb = 0; nb < 4; ++nb)
            #pragma unroll
            for (int r = 0; r < 4; ++r) {
                int m = m0 + wm + mb * 16 + quad * 4 + r;
                int n = n0 + wn + nb * 16 + l15;
                float v = acc[mb][nb][r];
                int b = m >> 11, t = m & (TS - 1);
                int h = n >> 6,  d = n & (DD - 1);
                __bf16 hi = (__bf16)v;
                __bf16 lo = (__bf16)(v - (float)hi);
                size_t off = (z == 2)
                    ? ((((size_t)b * HH + h) * DD + d) * TS + t)
                    : ((((size_t)b * HH + h) * TS + t) * DD + d);
                Ch[off] = hi;
                Cl[off] = lo;
            }
}

// ---------------- fused MFMA flash attention, wave=head, fixed-max softmax ----------
// Pass A (no LDS/barriers): rf = 1/sum exp(s-MS).  Pass B: exact probs (identical
// recompute), PV, out1.  Barriers are LDS-only (no vmcnt drain): global stores and
// V prefetches stay in flight across them.
__global__ __launch_bounds__(256, 4) void attnF(
    const __bf16* __restrict__ Qh, const __bf16* __restrict__ Ql,
    const __bf16* __restrict__ Kh, const __bf16* __restrict__ Kl,
    const __bf16* __restrict__ VhT, const __bf16* __restrict__ VlT,
    __bf16* __restrict__ avh, __bf16* __restrict__ avl,
    float* __restrict__ out1, _Float16* __restrict__ pp)
{
    __shared__ unsigned Pt[4][32][68];   // packed (bf16 hi<<16 | lo), per-wave P tile
    const int tid = threadIdx.x, wave = tid >> 6, lane = tid & 63;
    const int quad = lane >> 4, l15 = lane & 15;
    // XCD-locality swizzle: each XCD works one (b,g) at a time (4 MB K/V set fits L2)
    const int linear = blockIdx.x + 64 * blockIdx.y + 256 * blockIdx.z;
    const int bg = (linear & 7) + 8 * (linear >> 9);
    const int tt = (linear >> 3) & 63;
    const int b = bg & 3, g = bg >> 2;
    const int t0 = tt * 32;
    const int h = g * 4 + wave;
    const size_t hoff = (size_t)(b * HH + h);
    const __bf16* qhp = Qh + hoff * TS * DD;
    const __bf16* qlp = Ql + hoff * TS * DD;
    const __bf16* khp = Kh + hoff * TS * DD;
    const __bf16* klp = Kl + hoff * TS * DD;
    const __bf16* vhp = VhT + hoff * DD * TS;
    const __bf16* vlp = VlT + hoff * DD * TS;
    _Float16* myp = pp + (size_t)(g - 1) * ((size_t)BB * TS * TS);  // valid only when g>0

    // Q fragments in registers for the whole kernel
    bf16x8 fqh[2][2], fql[2][2];
    #pragma unroll
    for (int tb = 0; tb < 2; ++tb)
        #pragma unroll
        for (int ks = 0; ks < 2; ++ks) {
            size_t o = (size_t)(t0 + tb * 16 + l15) * DD + ks * 32 + quad * 8;
            fqh[tb][ks] = *(const bf16x8*)(qhp + o);
            fql[tb][ks] = *(const bf16x8*)(qlp + o);
        }

    // ---- pass A: l = sum exp(s - MS); no barriers, no LDS ----
    float lacc[2][4];
    #pragma unroll
    for (int tb = 0; tb < 2; ++tb)
        #pragma unroll
        for (int r = 0; r < 4; ++r) lacc[tb][r] = 0.f;

    for (int st = 0; st < 32; ++st) {
        bf16x8 kh[4][2], kl[4][2];
        #pragma unroll
        for (int sb = 0; sb < 4; ++sb) {
            size_t ko = (size_t)(st * 64 + sb * 16 + l15) * DD + quad * 8;
            kh[sb][0] = *(const bf16x8*)(khp + ko);
            kh[sb][1] = *(const bf16x8*)(khp + ko + 32);
            kl[sb][0] = *(const bf16x8*)(klp + ko);
            kl[sb][1] = *(const bf16x8*)(klp + ko + 32);
        }
        #pragma unroll
        for (int sb = 0; sb < 4; ++sb)
            #pragma unroll
            for (int tb = 0; tb < 2; ++tb) {
                f32x4 c = (f32x4){0.f, 0.f, 0.f, 0.f};
                c = mm3(fqh[tb][0], fql[tb][0], kh[sb][0], kl[sb][0], c);
                c = mm3(fqh[tb][1], fql[tb][1], kh[sb][1], kl[sb][1], c);
                #pragma unroll
                for (int r = 0; r < 4; ++r)
                    lacc[tb][r] += __expf(c[r] * 0.125f - MS);
            }
    }
    float rf[2][4];
    #pragma unroll
    for (int tb = 0; tb < 2; ++tb)
        #pragma unroll
        for (int r = 0; r < 4; ++r) {
            float v = lacc[tb][r];
            v += __shfl_xor(v, 1);
            v += __shfl_xor(v, 2);
            v += __shfl_xor(v, 4);
            v += __shfl_xor(v, 8);
            rf[tb][r] = 1.0f / v;
        }

    // ---- pass B: exact probs (bitwise-identical score recompute), PV, out1 ----
    f32x4 oacc[2][4];
    #pragma unroll
    for (int tb = 0; tb < 2; ++tb)
        #pragma unroll
        for (int db = 0; db < 4; ++db) oacc[tb][db] = (f32x4){0.f, 0.f, 0.f, 0.f};

    for (int st = 0; st < 32; ++st) {
        bf16x8 kh[4][2], kl[4][2];
        #pragma unroll
        for (int sb = 0; sb < 4; ++sb) {
            size_t ko = (size_t)(st * 64 + sb * 16 + l15) * DD + quad * 8;
            kh[sb][0] = *(const bf16x8*)(khp + ko);
            kh[sb][1] = *(const bf16x8*)(khp + ko + 32);
            kl[sb][0] = *(const bf16x8*)(klp + ko);
            kl[sb][1] = *(const bf16x8*)(klp + ko + 32);
        }
        #pragma unroll
        for (int sb = 0; sb < 4; ++sb)
            #pragma unroll
            for (int tb = 0; tb < 2; ++tb) {
                f32x4 c = (f32x4){0.f, 0.f, 0.f, 0.f};
                c = mm3(fqh[tb][0], fql[tb][0], kh[sb][0], kl[sb][0], c);
                c = mm3(fqh[tb][1], fql[tb][1], kh[sb][1], kl[sb][1], c);
                #pragma unroll
                for (int r = 0; r < 4; ++r) {
                    float p = __expf(c[r] * 0.125f - MS) * rf[tb][r];
                    Pt[wave][tb * 16 + quad * 4 + r][sb * 16 + l15] = pk2(p);
                }
            }
        LBAR();   // LDS-only: Pt writes visible; globals stay in flight

        // issue all 16 V loads first: their latency covers LDS reads + out1 reduce
        bf16x8 vh[4][2], vl[4][2];
        #pragma unroll
        for (int db = 0; db < 4; ++db) {
            size_t vo = (size_t)(db * 16 + l15) * TS + st * 64 + quad * 8;
            vh[db][0] = *(const bf16x8*)(vhp + vo);
            vh[db][1] = *(const bf16x8*)(vhp + vo + 32);
            vl[db][0] = *(const bf16x8*)(vlp + vo);
            vl[db][1] = *(const bf16x8*)(vlp + vo + 32);
        }

        // PV: P A-fragments from own wave's LDS region (v_perm unpack)
        bf16x8 fph[2][2], fpl[2][2];
        #pragma unroll
        for (int tb = 0; tb < 2; ++tb)
            #pragma unroll
            for (int ks = 0; ks < 2; ++ks) {
                const unsigned* ppt = &Pt[wave][tb * 16 + l15][ks * 32 + quad * 8];
                uint4 a = *(const uint4*)ppt;
                uint4 bq = *(const uint4*)(ppt + 4);
                fph[tb][ks] = sel_frag(a, bq, 0x07060302u);
                fpl[tb][ks] = sel_frag(a, bq, 0x05040100u);
            }

        // out1 partial: cross-wave (4-head) sum -> one plain vector store per thread
        {
            int row = tid >> 3, s8 = (tid & 7) * 8;
            float vs[8] = {0.f, 0.f, 0.f, 0.f, 0.f, 0.f, 0.f, 0.f};
            #pragma unroll
            for (int w = 0; w < 4; ++w) {
                const unsigned* pw = &Pt[w][row][s8];
                uint4 a = *(const uint4*)pw;
                uint4 bq = *(const uint4*)(pw + 4);
                unsigned uu[8] = {a.x, a.y, a.z, a.w, bq.x, bq.y, bq.z, bq.w};
                #pragma unroll
                for (int j = 0; j < 8; ++j)
                    vs[j] += upk_hi(uu[j]) + upk_lo(uu[j]);
            }
            size_t off = ((size_t)b * TS + t0 + row) * TS + st * 64 + s8;
            if (g == 0) {
                float4 o0, o1v;
                o0.x = vs[0] * 0.0625f; o0.y = vs[1] * 0.0625f;
                o0.z = vs[2] * 0.0625f; o0.w = vs[3] * 0.0625f;
                o1v.x = vs[4] * 0.0625f; o1v.y = vs[5] * 0.0625f;
                o1v.z = vs[6] * 0.0625f; o1v.w = vs[7] * 0.0625f;
                *(float4*)(out1 + off) = o0;
                *(float4*)(out1 + off + 4) = o1v;
            } else {
                f16x8 hv;
                #pragma unroll
                for (int j = 0; j < 8; ++j)
                    hv[j] = (_Float16)(vs[j] * 0.0625f);
                *(f16x8*)(myp + off) = hv;
            }
        }

        #pragma unroll
        for (int db = 0; db < 4; ++db)
            #pragma unroll
            for (int tb = 0; tb < 2; ++tb) {
                f32x4 o = oacc[tb][db];
                o = mm3(fph[tb][0], fpl[tb][0], vh[db][0], vl[db][0], o);
                o = mm3(fph[tb][1], fpl[tb][1], vh[db][1], vl[db][1], o);
                oacc[tb][db] = o;
            }
        LBAR();   // all waves done reading Pt before next iteration overwrites
    }

    // epilogue: avec as hi/lo bf16 [B*T, H*D]
    #pragma unroll
    for (int tb = 0; tb < 2; ++tb)
        #pragma unroll
        for (int db = 0; db < 4; ++db)
            #pragma unroll
            for (int r = 0; r < 4; ++r) {
                int row = t0 + tb * 16 + quad * 4 + r;
                int col = h * 64 + db * 16 + l15;
                float v = oacc[tb][db][r];
                __bf16 hi = (__bf16)v;
                size_t o = ((size_t)b * TS + row) * EE + col;
                avh[o] = hi;
                avl[o] = (__bf16)(v - (float)hi);
            }
}

// ---------------- out1 += p1+p2+p3 (fp16 partials), streaming ----------------
__global__ __launch_bounds__(256) void redk(float* __restrict__ out1,
    const _Float16* __restrict__ pp)
{
    const size_t P = (size_t)BB * TS * TS;
    size_t i = ((size_t)blockIdx.x * 256 + threadIdx.x) * 8;
    float4 a = *(const float4*)(out1 + i);
    float4 c = *(const float4*)(out1 + i + 4);
    f16x8 q1 = *(const f16x8*)(pp + i);
    f16x8 q2 = *(const f16x8*)(pp + P + i);
    f16x8 q3 = *(const f16x8*)(pp + 2 * P + i);
    a.x += (float)q1[0] + (float)q2[0] + (float)q3[0];
    a.y += (float)q1[1] + (float)q2[1] + (float)q3[1];
    a.z += (float)q1[2] + (float)q2[2] + (float)q3[2];
    a.w += (float)q1[3] + (float)q2[3] + (float)q3[3];
    c.x += (float)q1[4] + (float)q2[4] + (float)q3[4];
    c.y += (float)q1[5] + (float)q2[5] + (float)q3[5];
    c.z += (float)q1[6] + (float)q2[6] + (float)q3[6];
    c.w += (float)q1[7] + (float)q2[7] + (float)q3[7];
    *(float4*)(out1 + i) = a;
    *(float4*)(out1 + i + 4) = c;
}

extern "C" void kernel_launch(void* const* d_in, const int* in_sizes, int n_in,
                              void* d_out, int out_size, void* d_ws, size_t ws_size,
                              hipStream_t stream)
{
    const float* query = (const float*)d_in[0];
    const float* key_  = (const float*)d_in[1];
    const float* value = (const float*)d_in[2];
    const float* Wq    = (const float*)d_in[3];
    const float* Wk    = (const float*)d_in[4];
    const float* Wv    = (const float*)d_in[5];
    const float* Wo    = (const float*)d_in[6];

    float* out0 = (float*)d_out;                 // [B,T,E]
    float* out1 = out0 + (size_t)BB * TS * EE;   // [B,T,S]

    char* base = (char*)d_ws;
    const size_t U = 16777216;                   // 16 MB: one bf16 half of an 8.4M-elem tensor
    __bf16* xqh = (__bf16*)(base + 0 * U);
    __bf16* xql = (__bf16*)(base + 1 * U);
    __bf16* xkh = (__bf16*)(base + 2 * U);
    __bf16* xkl = (__bf16*)(base + 3 * U);
    __bf16* xvh = (__bf16*)(base + 4 * U);
    __bf16* xvl = (__bf16*)(base + 5 * U);
    __bf16* Qhp = (__bf16*)(base + 6 * U);
    __bf16* Qlp = (__bf16*)(base + 7 * U);
    __bf16* Khp = (__bf16*)(base + 8 * U);
    __bf16* Klp = (__bf16*)(base + 9 * U);
    __bf16* VhT = (__bf16*)(base + 10 * U);
    __bf16* VlT = (__bf16*)(base + 11 * U);
    __bf16* avh = (__bf16*)(base + 12 * U);
    __bf16* avl = (__bf16*)(base + 13 * U);
    __bf16* wqh = (__bf16*)(base + 14 * U);
    __bf16* wql = wqh + 1048576;
    __bf16* wkh = wql + 1048576;
    __bf16* wkl = wkh + 1048576;
    __bf16* wvh = wkl + 1048576;
    __bf16* wvl = wvh + 1048576;
    __bf16* woh = wvl + 1048576;
    __bf16* wol = woh + 1048576;
    // fp16 out1 partials for g=1..3 alias the xq/xk/xv splits (dead after the
    // QKV GEMM completes): 3 * 32 MB = exactly the 6*U region.
    _Float16* pp = (_Float16*)(base + 0 * U);

    splitX<<<dim3(4096, 3), 256, 0, stream>>>(query, key_, value,
                                              xqh, xql, xkh, xkl, xvh, xvl);
    splitW<<<dim3(512, 4), 256, 0, stream>>>(Wq, Wk, Wv, Wo,
                                             wqh, wql, wkh, wkl, wvh, wvl, woh, wol);

    gemmQKV<<<dim3(8, 64, 3), 256, 0, stream>>>(xqh, xql, xkh, xkl, xvh, xvl,
                                                wqh, wql, wkh, wkl, wvh, wvl,
                                                Qhp, Qlp, Khp, Klp, VhT, VlT);

    attnF<<<dim3(64, 4, 4), 256, 0, stream>>>(Qhp, Qlp, Khp, Klp, VhT, VlT,
                                              avh, avl, out1, pp);

    redk<<<8192, 256, 0, stream>>>(out1, pp);

    gemm3<0><<<dim3(8, 64), 256, 0, stream>>>(avh, avl, woh, wol, out0,
                                              nullptr, nullptr, 8192, 1024, 1024);
}

// Round 4
// 1191.238 us; speedup vs baseline: 1.4110x; 1.4110x over previous
//
#include <hip/hip_runtime.h>
#include <math.h>

#define HH 16
#define DD 64
#define TS 2048
#define EE 1024
#define BB 4
#define MS 12.0f

typedef __attribute__((ext_vector_type(8))) __bf16 bf16x8;
typedef __attribute__((ext_vector_type(8))) _Float16 f16x8;
typedef __attribute__((ext_vector_type(4))) float f32x4;

// LDS-only barrier: sync LDS without draining vmcnt (global loads/stores stay in flight).
// Single asm block so no memory op can be scheduled between the wait and the barrier.
#define LBAR() asm volatile("s_waitcnt lgkmcnt(0)\n\ts_barrier" ::: "memory")

__device__ __forceinline__ f32x4 mm3(bf16x8 ah, bf16x8 al, bf16x8 bh, bf16x8 bl, f32x4 c) {
    c = __builtin_amdgcn_mfma_f32_16x16x32_bf16(ah, bh, c, 0, 0, 0);
    c = __builtin_amdgcn_mfma_f32_16x16x32_bf16(ah, bl, c, 0, 0, 0);
    c = __builtin_amdgcn_mfma_f32_16x16x32_bf16(al, bh, c, 0, 0, 0);
    return c;
}

__device__ __forceinline__ void gll16(const void* g, void* l) {
    __builtin_amdgcn_global_load_lds(
        (const __attribute__((address_space(1))) unsigned int*)g,
        (__attribute__((address_space(3))) unsigned int*)l, 16, 0, 0);
}

__device__ __forceinline__ unsigned pk2(float p) {
    __bf16 h = (__bf16)p;
    __bf16 l = (__bf16)(p - (float)h);
    return ((unsigned)__builtin_bit_cast(unsigned short, h) << 16) |
            (unsigned)__builtin_bit_cast(unsigned short, l);
}
__device__ __forceinline__ float upk_hi(unsigned u) { return __builtin_bit_cast(float, u & 0xffff0000u); }
__device__ __forceinline__ float upk_lo(unsigned u) { return __builtin_bit_cast(float, u << 16); }

__device__ __forceinline__ bf16x8 sel_frag(uint4 a, uint4 b, unsigned s) {
    uint4 r;
    r.x = __builtin_amdgcn_perm(a.y, a.x, s);
    r.y = __builtin_amdgcn_perm(a.w, a.z, s);
    r.z = __builtin_amdgcn_perm(b.y, b.x, s);
    r.w = __builtin_amdgcn_perm(b.w, b.z, s);
    return __builtin_bit_cast(bf16x8, r);
}

__device__ __forceinline__ void split8(const float* __restrict__ src,
    __bf16* __restrict__ hi, __bf16* __restrict__ lo, size_t i)
{
    float4 a = *(const float4*)(src + i);
    float4 b = *(const float4*)(src + i + 4);
    float v[8] = {a.x, a.y, a.z, a.w, b.x, b.y, b.z, b.w};
    bf16x8 h, l;
    #pragma unroll
    for (int j = 0; j < 8; ++j) {
        __bf16 x = (__bf16)v[j];
        h[j] = x;
        l[j] = (__bf16)(v[j] - (float)x);
    }
    *(bf16x8*)(hi + i) = h;
    *(bf16x8*)(lo + i) = l;
}

// ---------------- fp32 -> bf16 hi/lo split: q/k/v batched (y selects tensor) --------
__global__ __launch_bounds__(256) void splitX(
    const float* __restrict__ q, const float* __restrict__ k, const float* __restrict__ v,
    __bf16* __restrict__ qh, __bf16* __restrict__ ql,
    __bf16* __restrict__ kh, __bf16* __restrict__ kl,
    __bf16* __restrict__ vh, __bf16* __restrict__ vl)
{
    const int z = blockIdx.y;
    const float* src = z == 0 ? q : z == 1 ? k : v;
    __bf16* hi = z == 0 ? qh : z == 1 ? kh : vh;
    __bf16* lo = z == 0 ? ql : z == 1 ? kl : vl;
    size_t i = ((size_t)blockIdx.x * 256 + threadIdx.x) * 8;
    split8(src, hi, lo, i);
}

// ---------------- weights batched (y selects tensor) ----------------
__global__ __launch_bounds__(256) void splitW(
    const float* __restrict__ wq, const float* __restrict__ wk,
    const float* __restrict__ wv, const float* __restrict__ wo,
    __bf16* __restrict__ qh, __bf16* __restrict__ ql,
    __bf16* __restrict__ kh, __bf16* __restrict__ kl,
    __bf16* __restrict__ vh, __bf16* __restrict__ vl,
    __bf16* __restrict__ oh, __bf16* __restrict__ ol)
{
    const int z = blockIdx.y;
    const float* src = z == 0 ? wq : z == 1 ? wk : z == 2 ? wv : wo;
    __bf16* hi = z == 0 ? qh : z == 1 ? kh : z == 2 ? vh : oh;
    __bf16* lo = z == 0 ? ql : z == 1 ? kl : z == 2 ? vl : ol;
    size_t i = ((size_t)blockIdx.x * 256 + threadIdx.x) * 8;
    split8(src, hi, lo, i);
}

// ---------------- 3-term split-bf16 MFMA GEMM: C[M,N] = A[M,K]*B[N,K]^T ----------------
// OMODE 0: f32 C[M,N]
template<int OMODE>
__global__ __launch_bounds__(256) void gemm3(
    const __bf16* __restrict__ Ah, const __bf16* __restrict__ Al,
    const __bf16* __restrict__ Bh, const __bf16* __restrict__ Bl,
    float* __restrict__ Cf, __bf16* __restrict__ Ch, __bf16* __restrict__ Cl,
    int M, int N, int K)
{
    __shared__ __bf16 sA[2][128 * 32];
    __shared__ __bf16 sB[2][128 * 32];
    const int tid = threadIdx.x, wave = tid >> 6, lane = tid & 63;
    const int quad = lane >> 4, l15 = lane & 15;
    const int m0 = blockIdx.y * 128, n0 = blockIdx.x * 128;
    const int wm = (wave >> 1) * 64, wn = (wave & 1) * 64;
    const int srow = lane >> 2, scol = (lane & 3) * 8;

    f32x4 acc[4][4];
    #pragma unroll
    for (int i = 0; i < 4; ++i)
        #pragma unroll
        for (int j = 0; j < 4; ++j)
            acc[i][j] = (f32x4){0.f, 0.f, 0.f, 0.f};

    for (int k0 = 0; k0 < K; k0 += 32) {
        __syncthreads();
        #pragma unroll
        for (int i = 0; i < 2; ++i) {
            int c = wave * 2 + i;
            size_t ga = (size_t)(m0 + c * 16 + srow) * K + k0 + scol;
            size_t gb = (size_t)(n0 + c * 16 + srow) * K + k0 + scol;
            gll16(Ah + ga, &sA[0][c * 512]);
            gll16(Al + ga, &sA[1][c * 512]);
            gll16(Bh + gb, &sB[0][c * 512]);
            gll16(Bl + gb, &sB[1][c * 512]);
        }
        __syncthreads();
        bf16x8 fAh[4], fAl[4], fBh[4], fBl[4];
        #pragma unroll
        for (int mb = 0; mb < 4; ++mb) {
            int r = (wm + mb * 16 + l15) * 32 + quad * 8;
            fAh[mb] = *(const bf16x8*)&sA[0][r];
            fAl[mb] = *(const bf16x8*)&sA[1][r];
        }
        #pragma unroll
        for (int nb = 0; nb < 4; ++nb) {
            int r = (wn + nb * 16 + l15) * 32 + quad * 8;
            fBh[nb] = *(const bf16x8*)&sB[0][r];
            fBl[nb] = *(const bf16x8*)&sB[1][r];
        }
        #pragma unroll
        for (int mb = 0; mb < 4; ++mb)
            #pragma unroll
            for (int nb = 0; nb < 4; ++nb)
                acc[mb][nb] = mm3(fAh[mb], fAl[mb], fBh[nb], fBl[nb], acc[mb][nb]);
    }

    #pragma unroll
    for (int mb = 0; mb < 4; ++mb)
        #pragma unroll
        for (int nb = 0; nb < 4; ++nb)
            #pragma unroll
            for (int r = 0; r < 4; ++r) {
                int m = m0 + wm + mb * 16 + quad * 4 + r;
                int n = n0 + wn + nb * 16 + l15;
                float v = acc[mb][nb][r];
                Cf[(size_t)m * N + n] = v;
            }
}

// ---------------- batched QKV projection GEMM (z selects tensor) ----------------
// z=0: Q -> [B,H,T,D] hi/lo;  z=1: K -> [B,H,T,D];  z=2: V -> [B,H,D,T] (transposed)
__global__ __launch_bounds__(256) void gemmQKV(
    const __bf16* __restrict__ xqh, const __bf16* __restrict__ xql,
    const __bf16* __restrict__ xkh, const __bf16* __restrict__ xkl,
    const __bf16* __restrict__ xvh, const __bf16* __restrict__ xvl,
    const __bf16* __restrict__ wqh, const __bf16* __restrict__ wql,
    const __bf16* __restrict__ wkh, const __bf16* __restrict__ wkl,
    const __bf16* __restrict__ wvh, const __bf16* __restrict__ wvl,
    __bf16* __restrict__ Qh, __bf16* __restrict__ Ql,
    __bf16* __restrict__ Kh, __bf16* __restrict__ Kl,
    __bf16* __restrict__ Vh, __bf16* __restrict__ Vl)
{
    const int z = blockIdx.z;
    const __bf16* Ah = z == 0 ? xqh : z == 1 ? xkh : xvh;
    const __bf16* Al = z == 0 ? xql : z == 1 ? xkl : xvl;
    const __bf16* Bh = z == 0 ? wqh : z == 1 ? wkh : wvh;
    const __bf16* Bl = z == 0 ? wql : z == 1 ? wkl : wvl;
    __bf16* Ch = z == 0 ? Qh : z == 1 ? Kh : Vh;
    __bf16* Cl = z == 0 ? Ql : z == 1 ? Kl : Vl;
    const int K = EE;

    __shared__ __bf16 sA[2][128 * 32];
    __shared__ __bf16 sB[2][128 * 32];
    const int tid = threadIdx.x, wave = tid >> 6, lane = tid & 63;
    const int quad = lane >> 4, l15 = lane & 15;
    const int m0 = blockIdx.y * 128, n0 = blockIdx.x * 128;
    const int wm = (wave >> 1) * 64, wn = (wave & 1) * 64;
    const int srow = lane >> 2, scol = (lane & 3) * 8;

    f32x4 acc[4][4];
    #pragma unroll
    for (int i = 0; i < 4; ++i)
        #pragma unroll
        for (int j = 0; j < 4; ++j)
            acc[i][j] = (f32x4){0.f, 0.f, 0.f, 0.f};

    for (int k0 = 0; k0 < K; k0 += 32) {
        __syncthreads();
        #pragma unroll
        for (int i = 0; i < 2; ++i) {
            int c = wave * 2 + i;
            size_t ga = (size_t)(m0 + c * 16 + srow) * K + k0 + scol;
            size_t gb = (size_t)(n0 + c * 16 + srow) * K + k0 + scol;
            gll16(Ah + ga, &sA[0][c * 512]);
            gll16(Al + ga, &sA[1][c * 512]);
            gll16(Bh + gb, &sB[0][c * 512]);
            gll16(Bl + gb, &sB[1][c * 512]);
        }
        __syncthreads();
        bf16x8 fAh[4], fAl[4], fBh[4], fBl[4];
        #pragma unroll
        for (int mb = 0; mb < 4; ++mb) {
            int r = (wm + mb * 16 + l15) * 32 + quad * 8;
            fAh[mb] = *(const bf16x8*)&sA[0][r];
            fAl[mb] = *(const bf16x8*)&sA[1][r];
        }
        #pragma unroll
        for (int nb = 0; nb < 4; ++nb) {
            int r = (wn + nb * 16 + l15) * 32 + quad * 8;
            fBh[nb] = *(const bf16x8*)&sB[0][r];
            fBl[nb] = *(const bf16x8*)&sB[1][r];
        }
        #pragma unroll
        for (int mb = 0; mb < 4; ++mb)
            #pragma unroll
            for (int nb = 0; nb < 4; ++nb)
                acc[mb][nb] = mm3(fAh[mb], fAl[mb], fBh[nb], fBl[nb], acc[mb][nb]);
    }

    #pragma unroll
    for (int mb = 0; mb < 4; ++mb)
        #pragma unroll
        for (int nb = 0; nb < 4; ++nb)
            #pragma unroll
            for (int r = 0; r < 4; ++r) {
                int m = m0 + wm + mb * 16 + quad * 4 + r;
                int n = n0 + wn + nb * 16 + l15;
                float v = acc[mb][nb][r];
                int b = m >> 11, t = m & (TS - 1);
                int h = n >> 6,  d = n & (DD - 1);
                __bf16 hi = (__bf16)v;
                __bf16 lo = (__bf16)(v - (float)hi);
                size_t off = (z == 2)
                    ? ((((size_t)b * HH + h) * DD + d) * TS + t)
                    : ((((size_t)b * HH + h) * TS + t) * DD + d);
                Ch[off] = hi;
                Cl[off] = lo;
            }
}

// ---------------- fused MFMA flash attention, wave=head, fixed-max softmax ----------
// Pass A (no LDS/barriers): rf = 1/sum exp(s-MS).  Pass B: exact probs (identical
// recompute), PV, out1.  Barriers are LDS-only (no vmcnt drain): global stores and
// V prefetches stay in flight across them.
// NOTE: plain __launch_bounds__(256) — do NOT add a min-waves clamp; forcing VGPR<=64
// spills the K-fragment prefetch to scratch (round-3 regression: FETCH 59MB->1.3GB).
__global__ __launch_bounds__(256) void attnF(
    const __bf16* __restrict__ Qh, const __bf16* __restrict__ Ql,
    const __bf16* __restrict__ Kh, const __bf16* __restrict__ Kl,
    const __bf16* __restrict__ VhT, const __bf16* __restrict__ VlT,
    __bf16* __restrict__ avh, __bf16* __restrict__ avl,
    float* __restrict__ out1, _Float16* __restrict__ pp)
{
    __shared__ unsigned Pt[4][32][68];   // packed (bf16 hi<<16 | lo), per-wave P tile
    const int tid = threadIdx.x, wave = tid >> 6, lane = tid & 63;
    const int quad = lane >> 4, l15 = lane & 15;
    // XCD-locality swizzle: each XCD works one (b,g) at a time (4 MB K/V set fits L2)
    const int linear = blockIdx.x + 64 * blockIdx.y + 256 * blockIdx.z;
    const int bg = (linear & 7) + 8 * (linear >> 9);
    const int tt = (linear >> 3) & 63;
    const int b = bg & 3, g = bg >> 2;
    const int t0 = tt * 32;
    const int h = g * 4 + wave;
    const size_t hoff = (size_t)(b * HH + h);
    const __bf16* qhp = Qh + hoff * TS * DD;
    const __bf16* qlp = Ql + hoff * TS * DD;
    const __bf16* khp = Kh + hoff * TS * DD;
    const __bf16* klp = Kl + hoff * TS * DD;
    const __bf16* vhp = VhT + hoff * DD * TS;
    const __bf16* vlp = VlT + hoff * DD * TS;
    _Float16* myp = pp + (size_t)(g - 1) * ((size_t)BB * TS * TS);  // valid only when g>0

    // Q fragments in registers for the whole kernel
    bf16x8 fqh[2][2], fql[2][2];
    #pragma unroll
    for (int tb = 0; tb < 2; ++tb)
        #pragma unroll
        for (int ks = 0; ks < 2; ++ks) {
            size_t o = (size_t)(t0 + tb * 16 + l15) * DD + ks * 32 + quad * 8;
            fqh[tb][ks] = *(const bf16x8*)(qhp + o);
            fql[tb][ks] = *(const bf16x8*)(qlp + o);
        }

    // ---- pass A: l = sum exp(s - MS); no barriers, no LDS ----
    float lacc[2][4];
    #pragma unroll
    for (int tb = 0; tb < 2; ++tb)
        #pragma unroll
        for (int r = 0; r < 4; ++r) lacc[tb][r] = 0.f;

    for (int st = 0; st < 32; ++st) {
        bf16x8 kh[4][2], kl[4][2];
        #pragma unroll
        for (int sb = 0; sb < 4; ++sb) {
            size_t ko = (size_t)(st * 64 + sb * 16 + l15) * DD + quad * 8;
            kh[sb][0] = *(const bf16x8*)(khp + ko);
            kh[sb][1] = *(const bf16x8*)(khp + ko + 32);
            kl[sb][0] = *(const bf16x8*)(klp + ko);
            kl[sb][1] = *(const bf16x8*)(klp + ko + 32);
        }
        #pragma unroll
        for (int sb = 0; sb < 4; ++sb)
            #pragma unroll
            for (int tb = 0; tb < 2; ++tb) {
                f32x4 c = (f32x4){0.f, 0.f, 0.f, 0.f};
                c = mm3(fqh[tb][0], fql[tb][0], kh[sb][0], kl[sb][0], c);
                c = mm3(fqh[tb][1], fql[tb][1], kh[sb][1], kl[sb][1], c);
                #pragma unroll
                for (int r = 0; r < 4; ++r)
                    lacc[tb][r] += __expf(c[r] * 0.125f - MS);
            }
    }
    float rf[2][4];
    #pragma unroll
    for (int tb = 0; tb < 2; ++tb)
        #pragma unroll
        for (int r = 0; r < 4; ++r) {
            float v = lacc[tb][r];
            v += __shfl_xor(v, 1);
            v += __shfl_xor(v, 2);
            v += __shfl_xor(v, 4);
            v += __shfl_xor(v, 8);
            rf[tb][r] = 1.0f / v;
        }

    // ---- pass B: exact probs (bitwise-identical score recompute), PV, out1 ----
    f32x4 oacc[2][4];
    #pragma unroll
    for (int tb = 0; tb < 2; ++tb)
        #pragma unroll
        for (int db = 0; db < 4; ++db) oacc[tb][db] = (f32x4){0.f, 0.f, 0.f, 0.f};

    for (int st = 0; st < 32; ++st) {
        bf16x8 kh[4][2], kl[4][2];
        #pragma unroll
        for (int sb = 0; sb < 4; ++sb) {
            size_t ko = (size_t)(st * 64 + sb * 16 + l15) * DD + quad * 8;
            kh[sb][0] = *(const bf16x8*)(khp + ko);
            kh[sb][1] = *(const bf16x8*)(khp + ko + 32);
            kl[sb][0] = *(const bf16x8*)(klp + ko);
            kl[sb][1] = *(const bf16x8*)(klp + ko + 32);
        }
        #pragma unroll
        for (int sb = 0; sb < 4; ++sb)
            #pragma unroll
            for (int tb = 0; tb < 2; ++tb) {
                f32x4 c = (f32x4){0.f, 0.f, 0.f, 0.f};
                c = mm3(fqh[tb][0], fql[tb][0], kh[sb][0], kl[sb][0], c);
                c = mm3(fqh[tb][1], fql[tb][1], kh[sb][1], kl[sb][1], c);
                #pragma unroll
                for (int r = 0; r < 4; ++r) {
                    float p = __expf(c[r] * 0.125f - MS) * rf[tb][r];
                    Pt[wave][tb * 16 + quad * 4 + r][sb * 16 + l15] = pk2(p);
                }
            }
        LBAR();   // LDS-only: Pt writes visible; globals stay in flight

        // issue all 16 V loads first: their latency covers LDS reads + out1 reduce
        bf16x8 vh[4][2], vl[4][2];
        #pragma unroll
        for (int db = 0; db < 4; ++db) {
            size_t vo = (size_t)(db * 16 + l15) * TS + st * 64 + quad * 8;
            vh[db][0] = *(const bf16x8*)(vhp + vo);
            vh[db][1] = *(const bf16x8*)(vhp + vo + 32);
            vl[db][0] = *(const bf16x8*)(vlp + vo);
            vl[db][1] = *(const bf16x8*)(vlp + vo + 32);
        }

        // PV: P A-fragments from own wave's LDS region (v_perm unpack)
        bf16x8 fph[2][2], fpl[2][2];
        #pragma unroll
        for (int tb = 0; tb < 2; ++tb)
            #pragma unroll
            for (int ks = 0; ks < 2; ++ks) {
                const unsigned* ppt = &Pt[wave][tb * 16 + l15][ks * 32 + quad * 8];
                uint4 a = *(const uint4*)ppt;
                uint4 bq = *(const uint4*)(ppt + 4);
                fph[tb][ks] = sel_frag(a, bq, 0x07060302u);
                fpl[tb][ks] = sel_frag(a, bq, 0x05040100u);
            }

        // out1 partial: cross-wave (4-head) sum -> one plain vector store per thread
        {
            int row = tid >> 3, s8 = (tid & 7) * 8;
            float vs[8] = {0.f, 0.f, 0.f, 0.f, 0.f, 0.f, 0.f, 0.f};
            #pragma unroll
            for (int w = 0; w < 4; ++w) {
                const unsigned* pw = &Pt[w][row][s8];
                uint4 a = *(const uint4*)pw;
                uint4 bq = *(const uint4*)(pw + 4);
                unsigned uu[8] = {a.x, a.y, a.z, a.w, bq.x, bq.y, bq.z, bq.w};
                #pragma unroll
                for (int j = 0; j < 8; ++j)
                    vs[j] += upk_hi(uu[j]) + upk_lo(uu[j]);
            }
            size_t off = ((size_t)b * TS + t0 + row) * TS + st * 64 + s8;
            if (g == 0) {
                float4 o0, o1v;
                o0.x = vs[0] * 0.0625f; o0.y = vs[1] * 0.0625f;
                o0.z = vs[2] * 0.0625f; o0.w = vs[3] * 0.0625f;
                o1v.x = vs[4] * 0.0625f; o1v.y = vs[5] * 0.0625f;
                o1v.z = vs[6] * 0.0625f; o1v.w = vs[7] * 0.0625f;
                *(float4*)(out1 + off) = o0;
                *(float4*)(out1 + off + 4) = o1v;
            } else {
                f16x8 hv;
                #pragma unroll
                for (int j = 0; j < 8; ++j)
                    hv[j] = (_Float16)(vs[j] * 0.0625f);
                *(f16x8*)(myp + off) = hv;
            }
        }

        #pragma unroll
        for (int db = 0; db < 4; ++db)
            #pragma unroll
            for (int tb = 0; tb < 2; ++tb) {
                f32x4 o = oacc[tb][db];
                o = mm3(fph[tb][0], fpl[tb][0], vh[db][0], vl[db][0], o);
                o = mm3(fph[tb][1], fpl[tb][1], vh[db][1], vl[db][1], o);
                oacc[tb][db] = o;
            }
        LBAR();   // all waves done reading Pt before next iteration overwrites
    }

    // epilogue: avec as hi/lo bf16 [B*T, H*D]
    #pragma unroll
    for (int tb = 0; tb < 2; ++tb)
        #pragma unroll
        for (int db = 0; db < 4; ++db)
            #pragma unroll
            for (int r = 0; r < 4; ++r) {
                int row = t0 + tb * 16 + quad * 4 + r;
                int col = h * 64 + db * 16 + l15;
                float v = oacc[tb][db][r];
                __bf16 hi = (__bf16)v;
                size_t o = ((size_t)b * TS + row) * EE + col;
                avh[o] = hi;
                avl[o] = (__bf16)(v - (float)hi);
            }
}

// ---------------- out1 += p1+p2+p3 (fp16 partials), streaming ----------------
__global__ __launch_bounds__(256) void redk(float* __restrict__ out1,
    const _Float16* __restrict__ pp)
{
    const size_t P = (size_t)BB * TS * TS;
    size_t i = ((size_t)blockIdx.x * 256 + threadIdx.x) * 8;
    float4 a = *(const float4*)(out1 + i);
    float4 c = *(const float4*)(out1 + i + 4);
    f16x8 q1 = *(const f16x8*)(pp + i);
    f16x8 q2 = *(const f16x8*)(pp + P + i);
    f16x8 q3 = *(const f16x8*)(pp + 2 * P + i);
    a.x += (float)q1[0] + (float)q2[0] + (float)q3[0];
    a.y += (float)q1[1] + (float)q2[1] + (float)q3[1];
    a.z += (float)q1[2] + (float)q2[2] + (float)q3[2];
    a.w += (float)q1[3] + (float)q2[3] + (float)q3[3];
    c.x += (float)q1[4] + (float)q2[4] + (float)q3[4];
    c.y += (float)q1[5] + (float)q2[5] + (float)q3[5];
    c.z += (float)q1[6] + (float)q2[6] + (float)q3[6];
    c.w += (float)q1[7] + (float)q2[7] + (float)q3[7];
    *(float4*)(out1 + i) = a;
    *(float4*)(out1 + i + 4) = c;
}

extern "C" void kernel_launch(void* const* d_in, const int* in_sizes, int n_in,
                              void* d_out, int out_size, void* d_ws, size_t ws_size,
                              hipStream_t stream)
{
    const float* query = (const float*)d_in[0];
    const float* key_  = (const float*)d_in[1];
    const float* value = (const float*)d_in[2];
    const float* Wq    = (const float*)d_in[3];
    const float* Wk    = (const float*)d_in[4];
    const float* Wv    = (const float*)d_in[5];
    const float* Wo    = (const float*)d_in[6];

    float* out0 = (float*)d_out;                 // [B,T,E]
    float* out1 = out0 + (size_t)BB * TS * EE;   // [B,T,S]

    char* base = (char*)d_ws;
    const size_t U = 16777216;                   // 16 MB: one bf16 half of an 8.4M-elem tensor
    __bf16* xqh = (__bf16*)(base + 0 * U);
    __bf16* xql = (__bf16*)(base + 1 * U);
    __bf16* xkh = (__bf16*)(base + 2 * U);
    __bf16* xkl = (__bf16*)(base + 3 * U);
    __bf16* xvh = (__bf16*)(base + 4 * U);
    __bf16* xvl = (__bf16*)(base + 5 * U);
    __bf16* Qhp = (__bf16*)(base + 6 * U);
    __bf16* Qlp = (__bf16*)(base + 7 * U);
    __bf16* Khp = (__bf16*)(base + 8 * U);
    __bf16* Klp = (__bf16*)(base + 9 * U);
    __bf16* VhT = (__bf16*)(base + 10 * U);
    __bf16* VlT = (__bf16*)(base + 11 * U);
    __bf16* avh = (__bf16*)(base + 12 * U);
    __bf16* avl = (__bf16*)(base + 13 * U);
    __bf16* wqh = (__bf16*)(base + 14 * U);
    __bf16* wql = wqh + 1048576;
    __bf16* wkh = wql + 1048576;
    __bf16* wkl = wkh + 1048576;
    __bf16* wvh = wkl + 1048576;
    __bf16* wvl = wvh + 1048576;
    __bf16* woh = wvl + 1048576;
    __bf16* wol = woh + 1048576;
    // fp16 out1 partials for g=1..3 alias the xq/xk/xv splits (dead after the
    // QKV GEMM completes): 3 * 32 MB = exactly the 6*U region.
    _Float16* pp = (_Float16*)(base + 0 * U);

    splitX<<<dim3(4096, 3), 256, 0, stream>>>(query, key_, value,
                                              xqh, xql, xkh, xkl, xvh, xvl);
    splitW<<<dim3(512, 4), 256, 0, stream>>>(Wq, Wk, Wv, Wo,
                                             wqh, wql, wkh, wkl, wvh, wvl, woh, wol);

    gemmQKV<<<dim3(8, 64, 3), 256, 0, stream>>>(xqh, xql, xkh, xkl, xvh, xvl,
                                                wqh, wql, wkh, wkl, wvh, wvl,
                                                Qhp, Qlp, Khp, Klp, VhT, VlT);

    attnF<<<dim3(64, 4, 4), 256, 0, stream>>>(Qhp, Qlp, Khp, Klp, VhT, VlT,
                                              avh, avl, out1, pp);

    redk<<<8192, 256, 0, stream>>>(out1, pp);

    gemm3<0><<<dim3(8, 64), 256, 0, stream>>>(avh, avl, woh, wol, out0,
                                              nullptr, nullptr, 8192, 1024, 1024);
}

// Round 6
// 1183.926 us; speedup vs baseline: 1.4197x; 1.0062x over previous
//
#include <hip/hip_runtime.h>
#include <math.h>

#define HH 16
#define DD 64
#define TS 2048
#define EE 1024
#define BB 4
#define MS 12.0f

typedef __attribute__((ext_vector_type(8))) __bf16 bf16x8;
typedef __attribute__((ext_vector_type(8))) _Float16 f16x8;
typedef __attribute__((ext_vector_type(4))) float f32x4;

// LDS-only barrier: sync LDS without draining vmcnt (global loads/stores stay in flight).
#define LBAR() asm volatile("s_waitcnt lgkmcnt(0)\n\ts_barrier" ::: "memory")

__device__ __forceinline__ f32x4 mm3(bf16x8 ah, bf16x8 al, bf16x8 bh, bf16x8 bl, f32x4 c) {
    c = __builtin_amdgcn_mfma_f32_16x16x32_bf16(ah, bh, c, 0, 0, 0);
    c = __builtin_amdgcn_mfma_f32_16x16x32_bf16(ah, bl, c, 0, 0, 0);
    c = __builtin_amdgcn_mfma_f32_16x16x32_bf16(al, bh, c, 0, 0, 0);
    return c;
}

__device__ __forceinline__ void gll16(const void* g, void* l) {
    __builtin_amdgcn_global_load_lds(
        (const __attribute__((address_space(1))) unsigned int*)g,
        (__attribute__((address_space(3))) unsigned int*)l, 16, 0, 0);
}

__device__ __forceinline__ unsigned pk2(float p) {
    __bf16 h = (__bf16)p;
    __bf16 l = (__bf16)(p - (float)h);
    return ((unsigned)__builtin_bit_cast(unsigned short, h) << 16) |
            (unsigned)__builtin_bit_cast(unsigned short, l);
}
__device__ __forceinline__ float upk_hi(unsigned u) { return __builtin_bit_cast(float, u & 0xffff0000u); }
__device__ __forceinline__ float upk_lo(unsigned u) { return __builtin_bit_cast(float, u << 16); }

__device__ __forceinline__ bf16x8 sel_frag(uint4 a, uint4 b, unsigned s) {
    uint4 r;
    r.x = __builtin_amdgcn_perm(a.y, a.x, s);
    r.y = __builtin_amdgcn_perm(a.w, a.z, s);
    r.z = __builtin_amdgcn_perm(b.y, b.x, s);
    r.w = __builtin_amdgcn_perm(b.w, b.z, s);
    return __builtin_bit_cast(bf16x8, r);
}

__device__ __forceinline__ void split8(const float* __restrict__ src,
    __bf16* __restrict__ hi, __bf16* __restrict__ lo, size_t i)
{
    float4 a = *(const float4*)(src + i);
    float4 b = *(const float4*)(src + i + 4);
    float v[8] = {a.x, a.y, a.z, a.w, b.x, b.y, b.z, b.w};
    bf16x8 h, l;
    #pragma unroll
    for (int j = 0; j < 8; ++j) {
        __bf16 x = (__bf16)v[j];
        h[j] = x;
        l[j] = (__bf16)(v[j] - (float)x);
    }
    *(bf16x8*)(hi + i) = h;
    *(bf16x8*)(lo + i) = l;
}

// ---------------- fp32 -> bf16 hi/lo split: q/k/v batched (y selects tensor) --------
__global__ __launch_bounds__(256) void splitX(
    const float* __restrict__ q, const float* __restrict__ k, const float* __restrict__ v,
    __bf16* __restrict__ qh, __bf16* __restrict__ ql,
    __bf16* __restrict__ kh, __bf16* __restrict__ kl,
    __bf16* __restrict__ vh, __bf16* __restrict__ vl)
{
    const int z = blockIdx.y;
    const float* src = z == 0 ? q : z == 1 ? k : v;
    __bf16* hi = z == 0 ? qh : z == 1 ? kh : vh;
    __bf16* lo = z == 0 ? ql : z == 1 ? kl : vl;
    size_t i = ((size_t)blockIdx.x * 256 + threadIdx.x) * 8;
    split8(src, hi, lo, i);
}

// ---------------- weights batched (y selects tensor) ----------------
__global__ __launch_bounds__(256) void splitW(
    const float* __restrict__ wq, const float* __restrict__ wk,
    const float* __restrict__ wv, const float* __restrict__ wo,
    __bf16* __restrict__ qh, __bf16* __restrict__ ql,
    __bf16* __restrict__ kh, __bf16* __restrict__ kl,
    __bf16* __restrict__ vh, __bf16* __restrict__ vl,
    __bf16* __restrict__ oh, __bf16* __restrict__ ol)
{
    const int z = blockIdx.y;
    const float* src = z == 0 ? wq : z == 1 ? wk : z == 2 ? wv : wo;
    __bf16* hi = z == 0 ? qh : z == 1 ? kh : z == 2 ? vh : oh;
    __bf16* lo = z == 0 ? ql : z == 1 ? kl : z == 2 ? vl : ol;
    size_t i = ((size_t)blockIdx.x * 256 + threadIdx.x) * 8;
    split8(src, hi, lo, i);
}

// ---------------- 3-term split-bf16 MFMA GEMM: C[M,N] = A[M,K]*B[N,K]^T ----------------
template<int OMODE>
__global__ __launch_bounds__(256) void gemm3(
    const __bf16* __restrict__ Ah, const __bf16* __restrict__ Al,
    const __bf16* __restrict__ Bh, const __bf16* __restrict__ Bl,
    float* __restrict__ Cf, __bf16* __restrict__ Ch, __bf16* __restrict__ Cl,
    int M, int N, int K)
{
    __shared__ __bf16 sA[2][128 * 32];
    __shared__ __bf16 sB[2][128 * 32];
    const int tid = threadIdx.x, wave = tid >> 6, lane = tid & 63;
    const int quad = lane >> 4, l15 = lane & 15;
    const int m0 = blockIdx.y * 128, n0 = blockIdx.x * 128;
    const int wm = (wave >> 1) * 64, wn = (wave & 1) * 64;
    const int srow = lane >> 2, scol = (lane & 3) * 8;

    f32x4 acc[4][4];
    #pragma unroll
    for (int i = 0; i < 4; ++i)
        #pragma unroll
        for (int j = 0; j < 4; ++j)
            acc[i][j] = (f32x4){0.f, 0.f, 0.f, 0.f};

    for (int k0 = 0; k0 < K; k0 += 32) {
        __syncthreads();
        #pragma unroll
        for (int i = 0; i < 2; ++i) {
            int c = wave * 2 + i;
            size_t ga = (size_t)(m0 + c * 16 + srow) * K + k0 + scol;
            size_t gb = (size_t)(n0 + c * 16 + srow) * K + k0 + scol;
            gll16(Ah + ga, &sA[0][c * 512]);
            gll16(Al + ga, &sA[1][c * 512]);
            gll16(Bh + gb, &sB[0][c * 512]);
            gll16(Bl + gb, &sB[1][c * 512]);
        }
        __syncthreads();
        bf16x8 fAh[4], fAl[4], fBh[4], fBl[4];
        #pragma unroll
        for (int mb = 0; mb < 4; ++mb) {
            int r = (wm + mb * 16 + l15) * 32 + quad * 8;
            fAh[mb] = *(const bf16x8*)&sA[0][r];
            fAl[mb] = *(const bf16x8*)&sA[1][r];
        }
        #pragma unroll
        for (int nb = 0; nb < 4; ++nb) {
            int r = (wn + nb * 16 + l15) * 32 + quad * 8;
            fBh[nb] = *(const bf16x8*)&sB[0][r];
            fBl[nb] = *(const bf16x8*)&sB[1][r];
        }
        #pragma unroll
        for (int mb = 0; mb < 4; ++mb)
            #pragma unroll
            for (int nb = 0; nb < 4; ++nb)
                acc[mb][nb] = mm3(fAh[mb], fAl[mb], fBh[nb], fBl[nb], acc[mb][nb]);
    }

    #pragma unroll
    for (int mb = 0; mb < 4; ++mb)
        #pragma unroll
        for (int nb = 0; nb < 4; ++nb)
            #pragma unroll
            for (int r = 0; r < 4; ++r) {
                int m = m0 + wm + mb * 16 + quad * 4 + r;
                int n = n0 + wn + nb * 16 + l15;
                float v = acc[mb][nb][r];
                Cf[(size_t)m * N + n] = v;
            }
}

// ---------------- batched QKV projection GEMM (z selects tensor) ----------------
__global__ __launch_bounds__(256) void gemmQKV(
    const __bf16* __restrict__ xqh, const __bf16* __restrict__ xql,
    const __bf16* __restrict__ xkh, const __bf16* __restrict__ xkl,
    const __bf16* __restrict__ xvh, const __bf16* __restrict__ xvl,
    const __bf16* __restrict__ wqh, const __bf16* __restrict__ wql,
    const __bf16* __restrict__ wkh, const __bf16* __restrict__ wkl,
    const __bf16* __restrict__ wvh, const __bf16* __restrict__ wvl,
    __bf16* __restrict__ Qh, __bf16* __restrict__ Ql,
    __bf16* __restrict__ Kh, __bf16* __restrict__ Kl,
    __bf16* __restrict__ Vh, __bf16* __restrict__ Vl)
{
    const int z = blockIdx.z;
    const __bf16* Ah = z == 0 ? xqh : z == 1 ? xkh : xvh;
    const __bf16* Al = z == 0 ? xql : z == 1 ? xkl : xvl;
    const __bf16* Bh = z == 0 ? wqh : z == 1 ? wkh : wvh;
    const __bf16* Bl = z == 0 ? wql : z == 1 ? wkl : wvl;
    __bf16* Ch = z == 0 ? Qh : z == 1 ? Kh : Vh;
    __bf16* Cl = z == 0 ? Ql : z == 1 ? Kl : Vl;
    const int K = EE;

    __shared__ __bf16 sA[2][128 * 32];
    __shared__ __bf16 sB[2][128 * 32];
    const int tid = threadIdx.x, wave = tid >> 6, lane = tid & 63;
    const int quad = lane >> 4, l15 = lane & 15;
    const int m0 = blockIdx.y * 128, n0 = blockIdx.x * 128;
    const int wm = (wave >> 1) * 64, wn = (wave & 1) * 64;
    const int srow = lane >> 2, scol = (lane & 3) * 8;

    f32x4 acc[4][4];
    #pragma unroll
    for (int i = 0; i < 4; ++i)
        #pragma unroll
        for (int j = 0; j < 4; ++j)
            acc[i][j] = (f32x4){0.f, 0.f, 0.f, 0.f};

    for (int k0 = 0; k0 < K; k0 += 32) {
        __syncthreads();
        #pragma unroll
        for (int i = 0; i < 2; ++i) {
            int c = wave * 2 + i;
            size_t ga = (size_t)(m0 + c * 16 + srow) * K + k0 + scol;
            size_t gb = (size_t)(n0 + c * 16 + srow) * K + k0 + scol;
            gll16(Ah + ga, &sA[0][c * 512]);
            gll16(Al + ga, &sA[1][c * 512]);
            gll16(Bh + gb, &sB[0][c * 512]);
            gll16(Bl + gb, &sB[1][c * 512]);
        }
        __syncthreads();
        bf16x8 fAh[4], fAl[4], fBh[4], fBl[4];
        #pragma unroll
        for (int mb = 0; mb < 4; ++mb) {
            int r = (wm + mb * 16 + l15) * 32 + quad * 8;
            fAh[mb] = *(const bf16x8*)&sA[0][r];
            fAl[mb] = *(const bf16x8*)&sA[1][r];
        }
        #pragma unroll
        for (int nb = 0; nb < 4; ++nb) {
            int r = (wn + nb * 16 + l15) * 32 + quad * 8;
            fBh[nb] = *(const bf16x8*)&sB[0][r];
            fBl[nb] = *(const bf16x8*)&sB[1][r];
        }
        #pragma unroll
        for (int mb = 0; mb < 4; ++mb)
            #pragma unroll
            for (int nb = 0; nb < 4; ++nb)
                acc[mb][nb] = mm3(fAh[mb], fAl[mb], fBh[nb], fBl[nb], acc[mb][nb]);
    }

    #pragma unroll
    for (int mb = 0; mb < 4; ++mb)
        #pragma unroll
        for (int nb = 0; nb < 4; ++nb)
            #pragma unroll
            for (int r = 0; r < 4; ++r) {
                int m = m0 + wm + mb * 16 + quad * 4 + r;
                int n = n0 + wn + nb * 16 + l15;
                float v = acc[mb][nb][r];
                int b = m >> 11, t = m & (TS - 1);
                int h = n >> 6,  d = n & (DD - 1);
                __bf16 hi = (__bf16)v;
                __bf16 lo = (__bf16)(v - (float)hi);
                size_t off = (z == 2)
                    ? ((((size_t)b * HH + h) * DD + d) * TS + t)
                    : ((((size_t)b * HH + h) * TS + t) * DD + d);
                Ch[off] = hi;
                Cl[off] = lo;
            }
}

// ============ SINGLE-PASS attention with deferred normalization (big-ws path) ========
// One QK^T sweep: p = exp(s-MS) unnormalized. PV accumulates unnorm; O scaled by
// rf = 1/l at the end. Per-head unnorm p stored fp16 to Ph; rf stored to rfg;
// out1 normalized+head-averaged in redk2. LDS P-tile is WAVE-PRIVATE -> zero barriers.
__global__ __launch_bounds__(256) void attnS(
    const __bf16* __restrict__ Qh, const __bf16* __restrict__ Ql,
    const __bf16* __restrict__ Kh, const __bf16* __restrict__ Kl,
    const __bf16* __restrict__ VhT, const __bf16* __restrict__ VlT,
    __bf16* __restrict__ avh, __bf16* __restrict__ avl,
    _Float16* __restrict__ Ph, float* __restrict__ rfg)
{
    __shared__ unsigned Pt[4][32][68];   // packed (bf16 hi<<16 | lo), per-wave P tile
    const int tid = threadIdx.x, wave = tid >> 6, lane = tid & 63;
    const int quad = lane >> 4, l15 = lane & 15;
    const int linear = blockIdx.x + 64 * blockIdx.y + 256 * blockIdx.z;
    const int bg = (linear & 7) + 8 * (linear >> 9);
    const int tt = (linear >> 3) & 63;
    const int b = bg & 3, g = bg >> 2;
    const int t0 = tt * 32;
    const int h = g * 4 + wave;
    const size_t hoff = (size_t)(b * HH + h);
    const __bf16* qhp = Qh + hoff * TS * DD;
    const __bf16* qlp = Ql + hoff * TS * DD;
    const __bf16* khp = Kh + hoff * TS * DD;
    const __bf16* klp = Kl + hoff * TS * DD;
    const __bf16* vhp = VhT + hoff * DD * TS;
    const __bf16* vlp = VlT + hoff * DD * TS;

    // Q fragments in registers for the whole kernel
    bf16x8 fqh[2][2], fql[2][2];
    #pragma unroll
    for (int tb = 0; tb < 2; ++tb)
        #pragma unroll
        for (int ks = 0; ks < 2; ++ks) {
            size_t o = (size_t)(t0 + tb * 16 + l15) * DD + ks * 32 + quad * 8;
            fqh[tb][ks] = *(const bf16x8*)(qhp + o);
            fql[tb][ks] = *(const bf16x8*)(qlp + o);
        }

    float lacc[2][4];
    #pragma unroll
    for (int tb = 0; tb < 2; ++tb)
        #pragma unroll
        for (int r = 0; r < 4; ++r) lacc[tb][r] = 0.f;

    f32x4 oacc[2][4];
    #pragma unroll
    for (int tb = 0; tb < 2; ++tb)
        #pragma unroll
        for (int db = 0; db < 4; ++db) oacc[tb][db] = (f32x4){0.f, 0.f, 0.f, 0.f};

    // per-head unnorm-p store coords (own-wave LDS rows)
    const int prow = lane >> 1, pc0 = (lane & 1) * 32;

    for (int st = 0; st < 32; ++st) {
        // prefetch all 16 K fragments for this tile
        bf16x8 kh[4][2], kl[4][2];
        #pragma unroll
        for (int sb = 0; sb < 4; ++sb) {
            size_t ko = (size_t)(st * 64 + sb * 16 + l15) * DD + quad * 8;
            kh[sb][0] = *(const bf16x8*)(khp + ko);
            kh[sb][1] = *(const bf16x8*)(khp + ko + 32);
            kl[sb][0] = *(const bf16x8*)(klp + ko);
            kl[sb][1] = *(const bf16x8*)(klp + ko + 32);
        }
        #pragma unroll
        for (int sb = 0; sb < 4; ++sb)
            #pragma unroll
            for (int tb = 0; tb < 2; ++tb) {
                f32x4 c = (f32x4){0.f, 0.f, 0.f, 0.f};
                c = mm3(fqh[tb][0], fql[tb][0], kh[sb][0], kl[sb][0], c);
                c = mm3(fqh[tb][1], fql[tb][1], kh[sb][1], kl[sb][1], c);
                #pragma unroll
                for (int r = 0; r < 4; ++r) {
                    float p = __expf(c[r] * 0.125f - MS);  // unnormalized
                    lacc[tb][r] += p;
                    Pt[wave][tb * 16 + quad * 4 + r][sb * 16 + l15] = pk2(p);
                }
            }
        // no barrier: Pt[wave] is wave-private; same-wave LDS ordering via lgkmcnt

        // V prefetch: latency covered by unpack + Ph store below
        bf16x8 vh[4][2], vl[4][2];
        #pragma unroll
        for (int db = 0; db < 4; ++db) {
            size_t vo = (size_t)(db * 16 + l15) * TS + st * 64 + quad * 8;
            vh[db][0] = *(const bf16x8*)(vhp + vo);
            vh[db][1] = *(const bf16x8*)(vhp + vo + 32);
            vl[db][0] = *(const bf16x8*)(vlp + vo);
            vl[db][1] = *(const bf16x8*)(vlp + vo + 32);
        }

        // PV A-fragments from own wave's LDS region (v_perm unpack)
        bf16x8 fph[2][2], fpl[2][2];
        #pragma unroll
        for (int tb = 0; tb < 2; ++tb)
            #pragma unroll
            for (int ks = 0; ks < 2; ++ks) {
                const unsigned* ppt = &Pt[wave][tb * 16 + l15][ks * 32 + quad * 8];
                uint4 a = *(const uint4*)ppt;
                uint4 bq = *(const uint4*)(ppt + 4);
                fph[tb][ks] = sel_frag(a, bq, 0x07060302u);
                fpl[tb][ks] = sel_frag(a, bq, 0x05040100u);
            }

        // per-head unnorm p -> fp16 global (lane owns half a row: 32 cols = 64B)
        {
            const unsigned* pw = &Pt[wave][prow][pc0];
            _Float16* dst = Ph + (hoff * TS + t0 + prow) * TS + st * 64 + pc0;
            #pragma unroll
            for (int blk = 0; blk < 4; ++blk) {
                uint4 a = *(const uint4*)(pw + blk * 8);
                uint4 bq = *(const uint4*)(pw + blk * 8 + 4);
                unsigned uu[8] = {a.x, a.y, a.z, a.w, bq.x, bq.y, bq.z, bq.w};
                f16x8 hv;
                #pragma unroll
                for (int j = 0; j < 8; ++j)
                    hv[j] = (_Float16)(upk_hi(uu[j]) + upk_lo(uu[j]));
                *(f16x8*)(dst + blk * 8) = hv;
            }
        }

        #pragma unroll
        for (int db = 0; db < 4; ++db)
            #pragma unroll
            for (int tb = 0; tb < 2; ++tb) {
                f32x4 o = oacc[tb][db];
                o = mm3(fph[tb][0], fpl[tb][0], vh[db][0], vl[db][0], o);
                o = mm3(fph[tb][1], fpl[tb][1], vh[db][1], vl[db][1], o);
                oacc[tb][db] = o;
            }
    }

    // rf = 1/l (row sums via 16-lane butterfly), write rfg, scale O
    float rf[2][4];
    #pragma unroll
    for (int tb = 0; tb < 2; ++tb)
        #pragma unroll
        for (int r = 0; r < 4; ++r) {
            float v = lacc[tb][r];
            v += __shfl_xor(v, 1);
            v += __shfl_xor(v, 2);
            v += __shfl_xor(v, 4);
            v += __shfl_xor(v, 8);
            rf[tb][r] = 1.0f / v;
            if (l15 == 0)
                rfg[hoff * TS + t0 + tb * 16 + quad * 4 + r] = rf[tb][r];
        }

    // epilogue: avec = O * rf as hi/lo bf16 [B*T, H*D]
    #pragma unroll
    for (int tb = 0; tb < 2; ++tb)
        #pragma unroll
        for (int db = 0; db < 4; ++db)
            #pragma unroll
            for (int r = 0; r < 4; ++r) {
                int row = t0 + tb * 16 + quad * 4 + r;
                int col = h * 64 + db * 16 + l15;
                float v = oacc[tb][db][r] * rf[tb][r];
                __bf16 hi = (__bf16)v;
                size_t o = ((size_t)b * TS + row) * EE + col;
                avh[o] = hi;
                avl[o] = (__bf16)(v - (float)hi);
            }
}

// ---------------- out1 = (1/16) sum_h Ph[h] * rf[h]  (big-ws path) ----------------
__global__ __launch_bounds__(256) void redk2(float* __restrict__ out1,
    const _Float16* __restrict__ Ph, const float* __restrict__ rfg)
{
    const int blk = blockIdx.x;              // b*TS + t
    const int b = blk >> 11, t = blk & (TS - 1);
    const int s8 = threadIdx.x * 8;
    float acc[8] = {0.f, 0.f, 0.f, 0.f, 0.f, 0.f, 0.f, 0.f};
    #pragma unroll
    for (int h = 0; h < HH; ++h) {
        const size_t ho = (size_t)b * HH + h;
        float w = rfg[ho * TS + t] * 0.0625f;
        f16x8 q = *(const f16x8*)(Ph + (ho * TS + t) * TS + s8);
        #pragma unroll
        for (int j = 0; j < 8; ++j)
            acc[j] += (float)q[j] * w;
    }
    float4 o0, o1v;
    o0.x = acc[0]; o0.y = acc[1]; o0.z = acc[2]; o0.w = acc[3];
    o1v.x = acc[4]; o1v.y = acc[5]; o1v.z = acc[6]; o1v.w = acc[7];
    float* dst = out1 + ((size_t)b * TS + t) * TS + s8;
    *(float4*)dst = o0;
    *(float4*)(dst + 4) = o1v;
}

// ============ fallback two-pass attention (round-4 path, ws_size-limited) ============
__global__ __launch_bounds__(256) void attnF(
    const __bf16* __restrict__ Qh, const __bf16* __restrict__ Ql,
    const __bf16* __restrict__ Kh, const __bf16* __restrict__ Kl,
    const __bf16* __restrict__ VhT, const __bf16* __restrict__ VlT,
    __bf16* __restrict__ avh, __bf16* __restrict__ avl,
    float* __restrict__ out1, _Float16* __restrict__ pp)
{
    __shared__ unsigned Pt[4][32][68];
    const int tid = threadIdx.x, wave = tid >> 6, lane = tid & 63;
    const int quad = lane >> 4, l15 = lane & 15;
    const int linear = blockIdx.x + 64 * blockIdx.y + 256 * blockIdx.z;
    const int bg = (linear & 7) + 8 * (linear >> 9);
    const int tt = (linear >> 3) & 63;
    const int b = bg & 3, g = bg >> 2;
    const int t0 = tt * 32;
    const int h = g * 4 + wave;
    const size_t hoff = (size_t)(b * HH + h);
    const __bf16* qhp = Qh + hoff * TS * DD;
    const __bf16* qlp = Ql + hoff * TS * DD;
    const __bf16* khp = Kh + hoff * TS * DD;
    const __bf16* klp = Kl + hoff * TS * DD;
    const __bf16* vhp = VhT + hoff * DD * TS;
    const __bf16* vlp = VlT + hoff * DD * TS;
    _Float16* myp = pp + (size_t)(g - 1) * ((size_t)BB * TS * TS);

    bf16x8 fqh[2][2], fql[2][2];
    #pragma unroll
    for (int tb = 0; tb < 2; ++tb)
        #pragma unroll
        for (int ks = 0; ks < 2; ++ks) {
            size_t o = (size_t)(t0 + tb * 16 + l15) * DD + ks * 32 + quad * 8;
            fqh[tb][ks] = *(const bf16x8*)(qhp + o);
            fql[tb][ks] = *(const bf16x8*)(qlp + o);
        }

    float lacc[2][4];
    #pragma unroll
    for (int tb = 0; tb < 2; ++tb)
        #pragma unroll
        for (int r = 0; r < 4; ++r) lacc[tb][r] = 0.f;

    for (int st = 0; st < 32; ++st) {
        bf16x8 kh[4][2], kl[4][2];
        #pragma unroll
        for (int sb = 0; sb < 4; ++sb) {
            size_t ko = (size_t)(st * 64 + sb * 16 + l15) * DD + quad * 8;
            kh[sb][0] = *(const bf16x8*)(khp + ko);
            kh[sb][1] = *(const bf16x8*)(khp + ko + 32);
            kl[sb][0] = *(const bf16x8*)(klp + ko);
            kl[sb][1] = *(const bf16x8*)(klp + ko + 32);
        }
        #pragma unroll
        for (int sb = 0; sb < 4; ++sb)
            #pragma unroll
            for (int tb = 0; tb < 2; ++tb) {
                f32x4 c = (f32x4){0.f, 0.f, 0.f, 0.f};
                c = mm3(fqh[tb][0], fql[tb][0], kh[sb][0], kl[sb][0], c);
                c = mm3(fqh[tb][1], fql[tb][1], kh[sb][1], kl[sb][1], c);
                #pragma unroll
                for (int r = 0; r < 4; ++r)
                    lacc[tb][r] += __expf(c[r] * 0.125f - MS);
            }
    }
    float rf[2][4];
    #pragma unroll
    for (int tb = 0; tb < 2; ++tb)
        #pragma unroll
        for (int r = 0; r < 4; ++r) {
            float v = lacc[tb][r];
            v += __shfl_xor(v, 1);
            v += __shfl_xor(v, 2);
            v += __shfl_xor(v, 4);
            v += __shfl_xor(v, 8);
            rf[tb][r] = 1.0f / v;
        }

    f32x4 oacc[2][4];
    #pragma unroll
    for (int tb = 0; tb < 2; ++tb)
        #pragma unroll
        for (int db = 0; db < 4; ++db) oacc[tb][db] = (f32x4){0.f, 0.f, 0.f, 0.f};

    for (int st = 0; st < 32; ++st) {
        bf16x8 kh[4][2], kl[4][2];
        #pragma unroll
        for (int sb = 0; sb < 4; ++sb) {
            size_t ko = (size_t)(st * 64 + sb * 16 + l15) * DD + quad * 8;
            kh[sb][0] = *(const bf16x8*)(khp + ko);
            kh[sb][1] = *(const bf16x8*)(khp + ko + 32);
            kl[sb][0] = *(const bf16x8*)(klp + ko);
            kl[sb][1] = *(const bf16x8*)(klp + ko + 32);
        }
        #pragma unroll
        for (int sb = 0; sb < 4; ++sb)
            #pragma unroll
            for (int tb = 0; tb < 2; ++tb) {
                f32x4 c = (f32x4){0.f, 0.f, 0.f, 0.f};
                c = mm3(fqh[tb][0], fql[tb][0], kh[sb][0], kl[sb][0], c);
                c = mm3(fqh[tb][1], fql[tb][1], kh[sb][1], kl[sb][1], c);
                #pragma unroll
                for (int r = 0; r < 4; ++r) {
                    float p = __expf(c[r] * 0.125f - MS) * rf[tb][r];
                    Pt[wave][tb * 16 + quad * 4 + r][sb * 16 + l15] = pk2(p);
                }
            }
        LBAR();

        bf16x8 vh[4][2], vl[4][2];
        #pragma unroll
        for (int db = 0; db < 4; ++db) {
            size_t vo = (size_t)(db * 16 + l15) * TS + st * 64 + quad * 8;
            vh[db][0] = *(const bf16x8*)(vhp + vo);
            vh[db][1] = *(const bf16x8*)(vhp + vo + 32);
            vl[db][0] = *(const bf16x8*)(vlp + vo);
            vl[db][1] = *(const bf16x8*)(vlp + vo + 32);
        }

        bf16x8 fph[2][2], fpl[2][2];
        #pragma unroll
        for (int tb = 0; tb < 2; ++tb)
            #pragma unroll
            for (int ks = 0; ks < 2; ++ks) {
                const unsigned* ppt = &Pt[wave][tb * 16 + l15][ks * 32 + quad * 8];
                uint4 a = *(const uint4*)ppt;
                uint4 bq = *(const uint4*)(ppt + 4);
                fph[tb][ks] = sel_frag(a, bq, 0x07060302u);
                fpl[tb][ks] = sel_frag(a, bq, 0x05040100u);
            }

        {
            int row = tid >> 3, s8 = (tid & 7) * 8;
            float vs[8] = {0.f, 0.f, 0.f, 0.f, 0.f, 0.f, 0.f, 0.f};
            #pragma unroll
            for (int w = 0; w < 4; ++w) {
                const unsigned* pw = &Pt[w][row][s8];
                uint4 a = *(const uint4*)pw;
                uint4 bq = *(const uint4*)(pw + 4);
                unsigned uu[8] = {a.x, a.y, a.z, a.w, bq.x, bq.y, bq.z, bq.w};
                #pragma unroll
                for (int j = 0; j < 8; ++j)
                    vs[j] += upk_hi(uu[j]) + upk_lo(uu[j]);
            }
            size_t off = ((size_t)b * TS + t0 + row) * TS + st * 64 + s8;
            if (g == 0) {
                float4 o0, o1v;
                o0.x = vs[0] * 0.0625f; o0.y = vs[1] * 0.0625f;
                o0.z = vs[2] * 0.0625f; o0.w = vs[3] * 0.0625f;
                o1v.x = vs[4] * 0.0625f; o1v.y = vs[5] * 0.0625f;
                o1v.z = vs[6] * 0.0625f; o1v.w = vs[7] * 0.0625f;
                *(float4*)(out1 + off) = o0;
                *(float4*)(out1 + off + 4) = o1v;
            } else {
                f16x8 hv;
                #pragma unroll
                for (int j = 0; j < 8; ++j)
                    hv[j] = (_Float16)(vs[j] * 0.0625f);
                *(f16x8*)(myp + off) = hv;
            }
        }

        #pragma unroll
        for (int db = 0; db < 4; ++db)
            #pragma unroll
            for (int tb = 0; tb < 2; ++tb) {
                f32x4 o = oacc[tb][db];
                o = mm3(fph[tb][0], fpl[tb][0], vh[db][0], vl[db][0], o);
                o = mm3(fph[tb][1], fpl[tb][1], vh[db][1], vl[db][1], o);
                oacc[tb][db] = o;
            }
        LBAR();
    }

    #pragma unroll
    for (int tb = 0; tb < 2; ++tb)
        #pragma unroll
        for (int db = 0; db < 4; ++db)
            #pragma unroll
            for (int r = 0; r < 4; ++r) {
                int row = t0 + tb * 16 + quad * 4 + r;
                int col = h * 64 + db * 16 + l15;
                float v = oacc[tb][db][r];
                __bf16 hi = (__bf16)v;
                size_t o = ((size_t)b * TS + row) * EE + col;
                avh[o] = hi;
                avl[o] = (__bf16)(v - (float)hi);
            }
}

// ---------------- out1 += p1+p2+p3 (fp16 partials, fallback) ----------------
__global__ __launch_bounds__(256) void redk(float* __restrict__ out1,
    const _Float16* __restrict__ pp)
{
    const size_t P = (size_t)BB * TS * TS;
    size_t i = ((size_t)blockIdx.x * 256 + threadIdx.x) * 8;
    float4 a = *(const float4*)(out1 + i);
    float4 c = *(const float4*)(out1 + i + 4);
    f16x8 q1 = *(const f16x8*)(pp + i);
    f16x8 q2 = *(const f16x8*)(pp + P + i);
    f16x8 q3 = *(const f16x8*)(pp + 2 * P + i);
    a.x += (float)q1[0] + (float)q2[0] + (float)q3[0];
    a.y += (float)q1[1] + (float)q2[1] + (float)q3[1];
    a.z += (float)q1[2] + (float)q2[2] + (float)q3[2];
    a.w += (float)q1[3] + (float)q2[3] + (float)q3[3];
    c.x += (float)q1[4] + (float)q2[4] + (float)q3[4];
    c.y += (float)q1[5] + (float)q2[5] + (float)q3[5];
    c.z += (float)q1[6] + (float)q2[6] + (float)q3[6];
    c.w += (float)q1[7] + (float)q2[7] + (float)q3[7];
    *(float4*)(out1 + i) = a;
    *(float4*)(out1 + i + 4) = c;
}

extern "C" void kernel_launch(void* const* d_in, const int* in_sizes, int n_in,
                              void* d_out, int out_size, void* d_ws, size_t ws_size,
                              hipStream_t stream)
{
    const float* query = (const float*)d_in[0];
    const float* key_  = (const float*)d_in[1];
    const float* value = (const float*)d_in[2];
    const float* Wq    = (const float*)d_in[3];
    const float* Wk    = (const float*)d_in[4];
    const float* Wv    = (const float*)d_in[5];
    const float* Wo    = (const float*)d_in[6];

    float* out0 = (float*)d_out;                 // [B,T,E]
    float* out1 = out0 + (size_t)BB * TS * EE;   // [B,T,S]

    char* base = (char*)d_ws;
    const size_t U = 16777216;
    __bf16* xqh = (__bf16*)(base + 0 * U);
    __bf16* xql = (__bf16*)(base + 1 * U);
    __bf16* xkh = (__bf16*)(base + 2 * U);
    __bf16* xkl = (__bf16*)(base + 3 * U);
    __bf16* xvh = (__bf16*)(base + 4 * U);
    __bf16* xvl = (__bf16*)(base + 5 * U);
    __bf16* Qhp = (__bf16*)(base + 6 * U);
    __bf16* Qlp = (__bf16*)(base + 7 * U);
    __bf16* Khp = (__bf16*)(base + 8 * U);
    __bf16* Klp = (__bf16*)(base + 9 * U);
    __bf16* VhT = (__bf16*)(base + 10 * U);
    __bf16* VlT = (__bf16*)(base + 11 * U);
    __bf16* avh = (__bf16*)(base + 12 * U);
    __bf16* avl = (__bf16*)(base + 13 * U);
    __bf16* wqh = (__bf16*)(base + 14 * U);
    __bf16* wql = wqh + 1048576;
    __bf16* wkh = wql + 1048576;
    __bf16* wkl = wkh + 1048576;
    __bf16* wvh = wkl + 1048576;
    __bf16* wvl = wvh + 1048576;
    __bf16* woh = wvl + 1048576;
    __bf16* wol = woh + 1048576;
    float*  rfg = (float*)(base + 15 * U);       // [B,H,T] fp32 = 512 KB
    _Float16* pp = (_Float16*)(base + 0 * U);    // fallback group partials
    _Float16* Ph = (_Float16*)(base + 16 * U);   // per-head unnorm p: 512 MB
    const size_t PH_BYTES = (size_t)BB * HH * TS * TS * sizeof(_Float16);
    const bool bigws = ws_size >= 16 * U + PH_BYTES;

    splitX<<<dim3(4096, 3), 256, 0, stream>>>(query, key_, value,
                                              xqh, xql, xkh, xkl, xvh, xvl);
    splitW<<<dim3(512, 4), 256, 0, stream>>>(Wq, Wk, Wv, Wo,
                                             wqh, wql, wkh, wkl, wvh, wvl, woh, wol);

    gemmQKV<<<dim3(8, 64, 3), 256, 0, stream>>>(xqh, xql, xkh, xkl, xvh, xvl,
                                                wqh, wql, wkh, wkl, wvh, wvl,
                                                Qhp, Qlp, Khp, Klp, VhT, VlT);

    if (bigws) {
        attnS<<<dim3(64, 4, 4), 256, 0, stream>>>(Qhp, Qlp, Khp, Klp, VhT, VlT,
                                                  avh, avl, Ph, rfg);
        redk2<<<BB * TS, 256, 0, stream>>>(out1, Ph, rfg);
    } else {
        attnF<<<dim3(64, 4, 4), 256, 0, stream>>>(Qhp, Qlp, Khp, Klp, VhT, VlT,
                                                  avh, avl, out1, pp);
        redk<<<8192, 256, 0, stream>>>(out1, pp);
    }

    gemm3<0><<<dim3(8, 64), 256, 0, stream>>>(avh, avl, woh, wol, out0,
                                              nullptr, nullptr, 8192, 1024, 1024);
}

// Round 7
// 857.545 us; speedup vs baseline: 1.9600x; 1.3806x over previous
//
#include <hip/hip_runtime.h>
#include <math.h>

#define HH 16
#define DD 64
#define TS 2048
#define EE 1024
#define BB 4
#define MS 12.0f

typedef __attribute__((ext_vector_type(8))) __bf16 bf16x8;
typedef __attribute__((ext_vector_type(8))) _Float16 f16x8;
typedef __attribute__((ext_vector_type(4))) float f32x4;

// LDS-only barrier: sync LDS without draining vmcnt (global loads/stores stay in flight).
#define LBAR() asm volatile("s_waitcnt lgkmcnt(0)\n\ts_barrier" ::: "memory")

__device__ __forceinline__ f32x4 mm3(bf16x8 ah, bf16x8 al, bf16x8 bh, bf16x8 bl, f32x4 c) {
    c = __builtin_amdgcn_mfma_f32_16x16x32_bf16(ah, bh, c, 0, 0, 0);
    c = __builtin_amdgcn_mfma_f32_16x16x32_bf16(ah, bl, c, 0, 0, 0);
    c = __builtin_amdgcn_mfma_f32_16x16x32_bf16(al, bh, c, 0, 0, 0);
    return c;
}

__device__ __forceinline__ void gll16(const void* g, void* l) {
    __builtin_amdgcn_global_load_lds(
        (const __attribute__((address_space(1))) unsigned int*)g,
        (__attribute__((address_space(3))) unsigned int*)l, 16, 0, 0);
}

__device__ __forceinline__ unsigned pk2(float p) {
    __bf16 h = (__bf16)p;
    __bf16 l = (__bf16)(p - (float)h);
    return ((unsigned)__builtin_bit_cast(unsigned short, h) << 16) |
            (unsigned)__builtin_bit_cast(unsigned short, l);
}
__device__ __forceinline__ float upk_hi(unsigned u) { return __builtin_bit_cast(float, u & 0xffff0000u); }
__device__ __forceinline__ float upk_lo(unsigned u) { return __builtin_bit_cast(float, u << 16); }

__device__ __forceinline__ bf16x8 sel_frag(uint4 a, uint4 b, unsigned s) {
    uint4 r;
    r.x = __builtin_amdgcn_perm(a.y, a.x, s);
    r.y = __builtin_amdgcn_perm(a.w, a.z, s);
    r.z = __builtin_amdgcn_perm(b.y, b.x, s);
    r.w = __builtin_amdgcn_perm(b.w, b.z, s);
    return __builtin_bit_cast(bf16x8, r);
}

__device__ __forceinline__ void split8(const float* __restrict__ src,
    __bf16* __restrict__ hi, __bf16* __restrict__ lo, size_t i)
{
    float4 a = *(const float4*)(src + i);
    float4 b = *(const float4*)(src + i + 4);
    float v[8] = {a.x, a.y, a.z, a.w, b.x, b.y, b.z, b.w};
    bf16x8 h, l;
    #pragma unroll
    for (int j = 0; j < 8; ++j) {
        __bf16 x = (__bf16)v[j];
        h[j] = x;
        l[j] = (__bf16)(v[j] - (float)x);
    }
    *(bf16x8*)(hi + i) = h;
    *(bf16x8*)(lo + i) = l;
}

// ---------------- fp32 -> bf16 hi/lo split: q/k/v batched (y selects tensor) --------
__global__ __launch_bounds__(256) void splitX(
    const float* __restrict__ q, const float* __restrict__ k, const float* __restrict__ v,
    __bf16* __restrict__ qh, __bf16* __restrict__ ql,
    __bf16* __restrict__ kh, __bf16* __restrict__ kl,
    __bf16* __restrict__ vh, __bf16* __restrict__ vl)
{
    const int z = blockIdx.y;
    const float* src = z == 0 ? q : z == 1 ? k : v;
    __bf16* hi = z == 0 ? qh : z == 1 ? kh : vh;
    __bf16* lo = z == 0 ? ql : z == 1 ? kl : vl;
    size_t i = ((size_t)blockIdx.x * 256 + threadIdx.x) * 8;
    split8(src, hi, lo, i);
}

// ---------------- weights batched (y selects tensor) ----------------
__global__ __launch_bounds__(256) void splitW(
    const float* __restrict__ wq, const float* __restrict__ wk,
    const float* __restrict__ wv, const float* __restrict__ wo,
    __bf16* __restrict__ qh, __bf16* __restrict__ ql,
    __bf16* __restrict__ kh, __bf16* __restrict__ kl,
    __bf16* __restrict__ vh, __bf16* __restrict__ vl,
    __bf16* __restrict__ oh, __bf16* __restrict__ ol)
{
    const int z = blockIdx.y;
    const float* src = z == 0 ? wq : z == 1 ? wk : z == 2 ? wv : wo;
    __bf16* hi = z == 0 ? qh : z == 1 ? kh : z == 2 ? vh : oh;
    __bf16* lo = z == 0 ? ql : z == 1 ? kl : z == 2 ? vl : ol;
    size_t i = ((size_t)blockIdx.x * 256 + threadIdx.x) * 8;
    split8(src, hi, lo, i);
}

// ---------------- 3-term split-bf16 MFMA GEMM: C[M,N] = A[M,K]*B[N,K]^T ----------------
template<int OMODE>
__global__ __launch_bounds__(256) void gemm3(
    const __bf16* __restrict__ Ah, const __bf16* __restrict__ Al,
    const __bf16* __restrict__ Bh, const __bf16* __restrict__ Bl,
    float* __restrict__ Cf, __bf16* __restrict__ Ch, __bf16* __restrict__ Cl,
    int M, int N, int K)
{
    __shared__ __bf16 sA[2][128 * 32];
    __shared__ __bf16 sB[2][128 * 32];
    const int tid = threadIdx.x, wave = tid >> 6, lane = tid & 63;
    const int quad = lane >> 4, l15 = lane & 15;
    const int m0 = blockIdx.y * 128, n0 = blockIdx.x * 128;
    const int wm = (wave >> 1) * 64, wn = (wave & 1) * 64;
    const int srow = lane >> 2, scol = (lane & 3) * 8;

    f32x4 acc[4][4];
    #pragma unroll
    for (int i = 0; i < 4; ++i)
        #pragma unroll
        for (int j = 0; j < 4; ++j)
            acc[i][j] = (f32x4){0.f, 0.f, 0.f, 0.f};

    for (int k0 = 0; k0 < K; k0 += 32) {
        __syncthreads();
        #pragma unroll
        for (int i = 0; i < 2; ++i) {
            int c = wave * 2 + i;
            size_t ga = (size_t)(m0 + c * 16 + srow) * K + k0 + scol;
            size_t gb = (size_t)(n0 + c * 16 + srow) * K + k0 + scol;
            gll16(Ah + ga, &sA[0][c * 512]);
            gll16(Al + ga, &sA[1][c * 512]);
            gll16(Bh + gb, &sB[0][c * 512]);
            gll16(Bl + gb, &sB[1][c * 512]);
        }
        __syncthreads();
        bf16x8 fAh[4], fAl[4], fBh[4], fBl[4];
        #pragma unroll
        for (int mb = 0; mb < 4; ++mb) {
            int r = (wm + mb * 16 + l15) * 32 + quad * 8;
            fAh[mb] = *(const bf16x8*)&sA[0][r];
            fAl[mb] = *(const bf16x8*)&sA[1][r];
        }
        #pragma unroll
        for (int nb = 0; nb < 4; ++nb) {
            int r = (wn + nb * 16 + l15) * 32 + quad * 8;
            fBh[nb] = *(const bf16x8*)&sB[0][r];
            fBl[nb] = *(const bf16x8*)&sB[1][r];
        }
        #pragma unroll
        for (int mb = 0; mb < 4; ++mb)
            #pragma unroll
            for (int nb = 0; nb < 4; ++nb)
                acc[mb][nb] = mm3(fAh[mb], fAl[mb], fBh[nb], fBl[nb], acc[mb][nb]);
    }

    #pragma unroll
    for (int mb = 0; mb < 4; ++mb)
        #pragma unroll
        for (int nb = 0; nb < 4; ++nb)
            #pragma unroll
            for (int r = 0; r < 4; ++r) {
                int m = m0 + wm + mb * 16 + quad * 4 + r;
                int n = n0 + wn + nb * 16 + l15;
                float v = acc[mb][nb][r];
                Cf[(size_t)m * N + n] = v;
            }
}

// ---------------- batched QKV projection GEMM (z selects tensor) ----------------
// Outputs are written in FRAGMENT-TILED layout per (b,h) head:
//   z=0,1 (Q,K as [T][D]):  tile(t>>4, d>>5) of 512 elems;
//       off = ((t>>4)*2 + (d>>5))*512 + (((d>>3)&3)*16 + (t&15))*8 + (d&7)
//   z=2 (V^T as [D][T]):    tile(d>>4, t>>5);
//       off = ((d>>4)*64 + (t>>5))*512 + (((t>>3)&3)*16 + (d&15))*8 + (t&7)
// so that a wave's MFMA-fragment load (lane = quad*16+l15, 8 elems) is one
// contiguous 1KB global load.
__global__ __launch_bounds__(256) void gemmQKV(
    const __bf16* __restrict__ xqh, const __bf16* __restrict__ xql,
    const __bf16* __restrict__ xkh, const __bf16* __restrict__ xkl,
    const __bf16* __restrict__ xvh, const __bf16* __restrict__ xvl,
    const __bf16* __restrict__ wqh, const __bf16* __restrict__ wql,
    const __bf16* __restrict__ wkh, const __bf16* __restrict__ wkl,
    const __bf16* __restrict__ wvh, const __bf16* __restrict__ wvl,
    __bf16* __restrict__ Qh, __bf16* __restrict__ Ql,
    __bf16* __restrict__ Kh, __bf16* __restrict__ Kl,
    __bf16* __restrict__ Vh, __bf16* __restrict__ Vl)
{
    const int z = blockIdx.z;
    const __bf16* Ah = z == 0 ? xqh : z == 1 ? xkh : xvh;
    const __bf16* Al = z == 0 ? xql : z == 1 ? xkl : xvl;
    const __bf16* Bh = z == 0 ? wqh : z == 1 ? wkh : wvh;
    const __bf16* Bl = z == 0 ? wql : z == 1 ? wkl : wvl;
    __bf16* Ch = z == 0 ? Qh : z == 1 ? Kh : Vh;
    __bf16* Cl = z == 0 ? Ql : z == 1 ? Kl : Vl;
    const int K = EE;

    __shared__ __bf16 sA[2][128 * 32];
    __shared__ __bf16 sB[2][128 * 32];
    const int tid = threadIdx.x, wave = tid >> 6, lane = tid & 63;
    const int quad = lane >> 4, l15 = lane & 15;
    const int m0 = blockIdx.y * 128, n0 = blockIdx.x * 128;
    const int wm = (wave >> 1) * 64, wn = (wave & 1) * 64;
    const int srow = lane >> 2, scol = (lane & 3) * 8;

    f32x4 acc[4][4];
    #pragma unroll
    for (int i = 0; i < 4; ++i)
        #pragma unroll
        for (int j = 0; j < 4; ++j)
            acc[i][j] = (f32x4){0.f, 0.f, 0.f, 0.f};

    for (int k0 = 0; k0 < K; k0 += 32) {
        __syncthreads();
        #pragma unroll
        for (int i = 0; i < 2; ++i) {
            int c = wave * 2 + i;
            size_t ga = (size_t)(m0 + c * 16 + srow) * K + k0 + scol;
            size_t gb = (size_t)(n0 + c * 16 + srow) * K + k0 + scol;
            gll16(Ah + ga, &sA[0][c * 512]);
            gll16(Al + ga, &sA[1][c * 512]);
            gll16(Bh + gb, &sB[0][c * 512]);
            gll16(Bl + gb, &sB[1][c * 512]);
        }
        __syncthreads();
        bf16x8 fAh[4], fAl[4], fBh[4], fBl[4];
        #pragma unroll
        for (int mb = 0; mb < 4; ++mb) {
            int r = (wm + mb * 16 + l15) * 32 + quad * 8;
            fAh[mb] = *(const bf16x8*)&sA[0][r];
            fAl[mb] = *(const bf16x8*)&sA[1][r];
        }
        #pragma unroll
        for (int nb = 0; nb < 4; ++nb) {
            int r = (wn + nb * 16 + l15) * 32 + quad * 8;
            fBh[nb] = *(const bf16x8*)&sB[0][r];
            fBl[nb] = *(const bf16x8*)&sB[1][r];
        }
        #pragma unroll
        for (int mb = 0; mb < 4; ++mb)
            #pragma unroll
            for (int nb = 0; nb < 4; ++nb)
                acc[mb][nb] = mm3(fAh[mb], fAl[mb], fBh[nb], fBl[nb], acc[mb][nb]);
    }

    #pragma unroll
    for (int mb = 0; mb < 4; ++mb)
        #pragma unroll
        for (int nb = 0; nb < 4; ++nb)
            #pragma unroll
            for (int r = 0; r < 4; ++r) {
                int m = m0 + wm + mb * 16 + quad * 4 + r;
                int n = n0 + wn + nb * 16 + l15;
                float v = acc[mb][nb][r];
                int b = m >> 11, t = m & (TS - 1);
                int h = n >> 6,  d = n & (DD - 1);
                __bf16 hi = (__bf16)v;
                __bf16 lo = (__bf16)(v - (float)hi);
                size_t hbase = ((size_t)b * HH + h) * TS * DD;
                size_t off;
                if (z == 2)
                    off = hbase + (size_t)(((d >> 4) * 64 + (t >> 5)) * 512
                          + (((t >> 3) & 3) * 16 + (d & 15)) * 8 + (d & 7) * 0 + (t & 7));
                else
                    off = hbase + (size_t)(((t >> 4) * 2 + (d >> 5)) * 512
                          + (((d >> 3) & 3) * 16 + (t & 15)) * 8 + (d & 7));
                Ch[off] = hi;
                Cl[off] = lo;
            }
}

// ---------------- two-pass MFMA flash attention, fragment-tiled Q/K/V ----------
// All Q/K/V fragment loads are contiguous 1KB wave-loads (tile*512 + lane*8).
// NOTE: plain __launch_bounds__(256) — do NOT add a min-waves clamp (round-3 spill).
__global__ __launch_bounds__(256) void attnF(
    const __bf16* __restrict__ Qh, const __bf16* __restrict__ Ql,
    const __bf16* __restrict__ Kh, const __bf16* __restrict__ Kl,
    const __bf16* __restrict__ VhT, const __bf16* __restrict__ VlT,
    __bf16* __restrict__ avh, __bf16* __restrict__ avl,
    float* __restrict__ out1, _Float16* __restrict__ pp)
{
    __shared__ unsigned Pt[4][32][68];
    const int tid = threadIdx.x, wave = tid >> 6, lane = tid & 63;
    const int quad = lane >> 4, l15 = lane & 15;
    const int linear = blockIdx.x + 64 * blockIdx.y + 256 * blockIdx.z;
    const int bg = (linear & 7) + 8 * (linear >> 9);
    const int tt = (linear >> 3) & 63;
    const int b = bg & 3, g = bg >> 2;
    const int t0 = tt * 32;
    const int h = g * 4 + wave;
    const size_t hoff = (size_t)(b * HH + h);
    const __bf16* qhp = Qh + hoff * TS * DD;
    const __bf16* qlp = Ql + hoff * TS * DD;
    const __bf16* khp = Kh + hoff * TS * DD;
    const __bf16* klp = Kl + hoff * TS * DD;
    const __bf16* vhp = VhT + hoff * DD * TS;
    const __bf16* vlp = VlT + hoff * DD * TS;
    _Float16* myp = pp + (size_t)(g - 1) * ((size_t)BB * TS * TS);

    const int loff = (quad * 16 + l15) * 8;   // lane offset within a 512-elem tile

    // Q fragments (tiled: tile index (t0>>4)+tb row, ks col-half)
    bf16x8 fqh[2][2], fql[2][2];
    #pragma unroll
    for (int tb = 0; tb < 2; ++tb)
        #pragma unroll
        for (int ks = 0; ks < 2; ++ks) {
            size_t o = (size_t)((((t0 >> 4) + tb) * 2 + ks) * 512 + loff);
            fqh[tb][ks] = *(const bf16x8*)(qhp + o);
            fql[tb][ks] = *(const bf16x8*)(qlp + o);
        }

    // ---- pass A: l = sum exp(s - MS); no barriers, no LDS ----
    float lacc[2][4];
    #pragma unroll
    for (int tb = 0; tb < 2; ++tb)
        #pragma unroll
        for (int r = 0; r < 4; ++r) lacc[tb][r] = 0.f;

    for (int st = 0; st < 32; ++st) {
        bf16x8 kh[4][2], kl[4][2];
        #pragma unroll
        for (int sb = 0; sb < 4; ++sb) {
            const int kt = ((st * 4 + sb) * 2) * 512 + loff;
            kh[sb][0] = *(const bf16x8*)(khp + kt);
            kh[sb][1] = *(const bf16x8*)(khp + kt + 512);
            kl[sb][0] = *(const bf16x8*)(klp + kt);
            kl[sb][1] = *(const bf16x8*)(klp + kt + 512);
        }
        #pragma unroll
        for (int sb = 0; sb < 4; ++sb)
            #pragma unroll
            for (int tb = 0; tb < 2; ++tb) {
                f32x4 c = (f32x4){0.f, 0.f, 0.f, 0.f};
                c = mm3(fqh[tb][0], fql[tb][0], kh[sb][0], kl[sb][0], c);
                c = mm3(fqh[tb][1], fql[tb][1], kh[sb][1], kl[sb][1], c);
                #pragma unroll
                for (int r = 0; r < 4; ++r)
                    lacc[tb][r] += __expf(c[r] * 0.125f - MS);
            }
    }
    float rf[2][4];
    #pragma unroll
    for (int tb = 0; tb < 2; ++tb)
        #pragma unroll
        for (int r = 0; r < 4; ++r) {
            float v = lacc[tb][r];
            v += __shfl_xor(v, 1);
            v += __shfl_xor(v, 2);
            v += __shfl_xor(v, 4);
            v += __shfl_xor(v, 8);
            rf[tb][r] = 1.0f / v;
        }

    // ---- pass B: exact probs (bitwise-identical score recompute), PV, out1 ----
    f32x4 oacc[2][4];
    #pragma unroll
    for (int tb = 0; tb < 2; ++tb)
        #pragma unroll
        for (int db = 0; db < 4; ++db) oacc[tb][db] = (f32x4){0.f, 0.f, 0.f, 0.f};

    for (int st = 0; st < 32; ++st) {
        bf16x8 kh[4][2], kl[4][2];
        #pragma unroll
        for (int sb = 0; sb < 4; ++sb) {
            const int kt = ((st * 4 + sb) * 2) * 512 + loff;
            kh[sb][0] = *(const bf16x8*)(khp + kt);
            kh[sb][1] = *(const bf16x8*)(khp + kt + 512);
            kl[sb][0] = *(const bf16x8*)(klp + kt);
            kl[sb][1] = *(const bf16x8*)(klp + kt + 512);
        }
        #pragma unroll
        for (int sb = 0; sb < 4; ++sb)
            #pragma unroll
            for (int tb = 0; tb < 2; ++tb) {
                f32x4 c = (f32x4){0.f, 0.f, 0.f, 0.f};
                c = mm3(fqh[tb][0], fql[tb][0], kh[sb][0], kl[sb][0], c);
                c = mm3(fqh[tb][1], fql[tb][1], kh[sb][1], kl[sb][1], c);
                #pragma unroll
                for (int r = 0; r < 4; ++r) {
                    float p = __expf(c[r] * 0.125f - MS) * rf[tb][r];
                    Pt[wave][tb * 16 + quad * 4 + r][sb * 16 + l15] = pk2(p);
                }
            }
        LBAR();

        // V fragments (tiled: tile (db, st*2+ks)) — contiguous 1KB wave-loads
        bf16x8 vh[4][2], vl[4][2];
        #pragma unroll
        for (int db = 0; db < 4; ++db) {
            const int vt = (db * 64 + st * 2) * 512 + loff;
            vh[db][0] = *(const bf16x8*)(vhp + vt);
            vh[db][1] = *(const bf16x8*)(vhp + vt + 512);
            vl[db][0] = *(const bf16x8*)(vlp + vt);
            vl[db][1] = *(const bf16x8*)(vlp + vt + 512);
        }

        bf16x8 fph[2][2], fpl[2][2];
        #pragma unroll
        for (int tb = 0; tb < 2; ++tb)
            #pragma unroll
            for (int ks = 0; ks < 2; ++ks) {
                const unsigned* ppt = &Pt[wave][tb * 16 + l15][ks * 32 + quad * 8];
                uint4 a = *(const uint4*)ppt;
                uint4 bq = *(const uint4*)(ppt + 4);
                fph[tb][ks] = sel_frag(a, bq, 0x07060302u);
                fpl[tb][ks] = sel_frag(a, bq, 0x05040100u);
            }

        {
            int row = tid >> 3, s8 = (tid & 7) * 8;
            float vs[8] = {0.f, 0.f, 0.f, 0.f, 0.f, 0.f, 0.f, 0.f};
            #pragma unroll
            for (int w = 0; w < 4; ++w) {
                const unsigned* pw = &Pt[w][row][s8];
                uint4 a = *(const uint4*)pw;
                uint4 bq = *(const uint4*)(pw + 4);
                unsigned uu[8] = {a.x, a.y, a.z, a.w, bq.x, bq.y, bq.z, bq.w};
                #pragma unroll
                for (int j = 0; j < 8; ++j)
                    vs[j] += upk_hi(uu[j]) + upk_lo(uu[j]);
            }
            size_t off = ((size_t)b * TS + t0 + row) * TS + st * 64 + s8;
            if (g == 0) {
                float4 o0, o1v;
                o0.x = vs[0] * 0.0625f; o0.y = vs[1] * 0.0625f;
                o0.z = vs[2] * 0.0625f; o0.w = vs[3] * 0.0625f;
                o1v.x = vs[4] * 0.0625f; o1v.y = vs[5] * 0.0625f;
                o1v.z = vs[6] * 0.0625f; o1v.w = vs[7] * 0.0625f;
                *(float4*)(out1 + off) = o0;
                *(float4*)(out1 + off + 4) = o1v;
            } else {
                f16x8 hv;
                #pragma unroll
                for (int j = 0; j < 8; ++j)
                    hv[j] = (_Float16)(vs[j] * 0.0625f);
                *(f16x8*)(myp + off) = hv;
            }
        }

        #pragma unroll
        for (int db = 0; db < 4; ++db)
            #pragma unroll
            for (int tb = 0; tb < 2; ++tb) {
                f32x4 o = oacc[tb][db];
                o = mm3(fph[tb][0], fpl[tb][0], vh[db][0], vl[db][0], o);
                o = mm3(fph[tb][1], fpl[tb][1], vh[db][1], vl[db][1], o);
                oacc[tb][db] = o;
            }
        LBAR();
    }

    // epilogue: avec as hi/lo bf16 [B*T, H*D]
    #pragma unroll
    for (int tb = 0; tb < 2; ++tb)
        #pragma unroll
        for (int db = 0; db < 4; ++db)
            #pragma unroll
            for (int r = 0; r < 4; ++r) {
                int row = t0 + tb * 16 + quad * 4 + r;
                int col = h * 64 + db * 16 + l15;
                float v = oacc[tb][db][r];
                __bf16 hi = (__bf16)v;
                size_t o = ((size_t)b * TS + row) * EE + col;
                avh[o] = hi;
                avl[o] = (__bf16)(v - (float)hi);
            }
}

// ---------------- out1 += p1+p2+p3 (fp16 partials), streaming ----------------
__global__ __launch_bounds__(256) void redk(float* __restrict__ out1,
    const _Float16* __restrict__ pp)
{
    const size_t P = (size_t)BB * TS * TS;
    size_t i = ((size_t)blockIdx.x * 256 + threadIdx.x) * 8;
    float4 a = *(const float4*)(out1 + i);
    float4 c = *(const float4*)(out1 + i + 4);
    f16x8 q1 = *(const f16x8*)(pp + i);
    f16x8 q2 = *(const f16x8*)(pp + P + i);
    f16x8 q3 = *(const f16x8*)(pp + 2 * P + i);
    a.x += (float)q1[0] + (float)q2[0] + (float)q3[0];
    a.y += (float)q1[1] + (float)q2[1] + (float)q3[1];
    a.z += (float)q1[2] + (float)q2[2] + (float)q3[2];
    a.w += (float)q1[3] + (float)q2[3] + (float)q3[3];
    c.x += (float)q1[4] + (float)q2[4] + (float)q3[4];
    c.y += (float)q1[5] + (float)q2[5] + (float)q3[5];
    c.z += (float)q1[6] + (float)q2[6] + (float)q3[6];
    c.w += (float)q1[7] + (float)q2[7] + (float)q3[7];
    *(float4*)(out1 + i) = a;
    *(float4*)(out1 + i + 4) = c;
}

extern "C" void kernel_launch(void* const* d_in, const int* in_sizes, int n_in,
                              void* d_out, int out_size, void* d_ws, size_t ws_size,
                              hipStream_t stream)
{
    const float* query = (const float*)d_in[0];
    const float* key_  = (const float*)d_in[1];
    const float* value = (const float*)d_in[2];
    const float* Wq    = (const float*)d_in[3];
    const float* Wk    = (const float*)d_in[4];
    const float* Wv    = (const float*)d_in[5];
    const float* Wo    = (const float*)d_in[6];

    float* out0 = (float*)d_out;                 // [B,T,E]
    float* out1 = out0 + (size_t)BB * TS * EE;   // [B,T,S]

    char* base = (char*)d_ws;
    const size_t U = 16777216;
    __bf16* xqh = (__bf16*)(base + 0 * U);
    __bf16* xql = (__bf16*)(base + 1 * U);
    __bf16* xkh = (__bf16*)(base + 2 * U);
    __bf16* xkl = (__bf16*)(base + 3 * U);
    __bf16* xvh = (__bf16*)(base + 4 * U);
    __bf16* xvl = (__bf16*)(base + 5 * U);
    __bf16* Qhp = (__bf16*)(base + 6 * U);
    __bf16* Qlp = (__bf16*)(base + 7 * U);
    __bf16* Khp = (__bf16*)(base + 8 * U);
    __bf16* Klp = (__bf16*)(base + 9 * U);
    __bf16* VhT = (__bf16*)(base + 10 * U);
    __bf16* VlT = (__bf16*)(base + 11 * U);
    __bf16* avh = (__bf16*)(base + 12 * U);
    __bf16* avl = (__bf16*)(base + 13 * U);
    __bf16* wqh = (__bf16*)(base + 14 * U);
    __bf16* wql = wqh + 1048576;
    __bf16* wkh = wql + 1048576;
    __bf16* wkl = wkh + 1048576;
    __bf16* wvh = wkl + 1048576;
    __bf16* wvl = wvh + 1048576;
    __bf16* woh = wvl + 1048576;
    __bf16* wol = woh + 1048576;
    // fp16 out1 partials for g=1..3 alias the xq/xk/xv splits (dead after gemmQKV)
    _Float16* pp = (_Float16*)(base + 0 * U);

    splitX<<<dim3(4096, 3), 256, 0, stream>>>(query, key_, value,
                                              xqh, xql, xkh, xkl, xvh, xvl);
    splitW<<<dim3(512, 4), 256, 0, stream>>>(Wq, Wk, Wv, Wo,
                                             wqh, wql, wkh, wkl, wvh, wvl, woh, wol);

    gemmQKV<<<dim3(8, 64, 3), 256, 0, stream>>>(xqh, xql, xkh, xkl, xvh, xvl,
                                                wqh, wql, wkh, wkl, wvh, wvl,
                                                Qhp, Qlp, Khp, Klp, VhT, VlT);

    attnF<<<dim3(64, 4, 4), 256, 0, stream>>>(Qhp, Qlp, Khp, Klp, VhT, VlT,
                                              avh, avl, out1, pp);

    redk<<<8192, 256, 0, stream>>>(out1, pp);

    gemm3<0><<<dim3(8, 64), 256, 0, stream>>>(avh, avl, woh, wol, out0,
                                              nullptr, nullptr, 8192, 1024, 1024);
}

// Round 8
// 849.550 us; speedup vs baseline: 1.9785x; 1.0094x over previous
//
#include <hip/hip_runtime.h>
#include <math.h>

#define HH 16
#define DD 64
#define TS 2048
#define EE 1024
#define BB 4
#define MS 12.0f

typedef __attribute__((ext_vector_type(8))) __bf16 bf16x8;
typedef __attribute__((ext_vector_type(2))) __bf16 bf16x2;
typedef __attribute__((ext_vector_type(8))) _Float16 f16x8;
typedef __attribute__((ext_vector_type(4))) float f32x4;

#if defined(__has_builtin)
#if __has_builtin(__builtin_amdgcn_fdot2_f32_bf16)
#define HAS_DOT2 1
#endif
#if __has_builtin(__builtin_amdgcn_exp2f)
#define EXP2(x) __builtin_amdgcn_exp2f(x)
#endif
#endif
#ifndef EXP2
#define EXP2(x) exp2f(x)
#endif

// p = exp(c*0.125 - MS) via single fma + native exp2 (identical in both passes)
__device__ __forceinline__ float pexp(float c) {
    return EXP2(__builtin_fmaf(c, 0.18033688011112042f, -17.312340490667562f));
}

// LDS-only barrier: sync LDS without draining vmcnt (global loads/stores stay in flight).
#define LBAR() asm volatile("s_waitcnt lgkmcnt(0)\n\ts_barrier" ::: "memory")

__device__ __forceinline__ f32x4 mm3(bf16x8 ah, bf16x8 al, bf16x8 bh, bf16x8 bl, f32x4 c) {
    c = __builtin_amdgcn_mfma_f32_16x16x32_bf16(ah, bh, c, 0, 0, 0);
    c = __builtin_amdgcn_mfma_f32_16x16x32_bf16(ah, bl, c, 0, 0, 0);
    c = __builtin_amdgcn_mfma_f32_16x16x32_bf16(al, bh, c, 0, 0, 0);
    return c;
}

__device__ __forceinline__ void gll16(const void* g, void* l) {
    __builtin_amdgcn_global_load_lds(
        (const __attribute__((address_space(1))) unsigned int*)g,
        (__attribute__((address_space(3))) unsigned int*)l, 16, 0, 0);
}

// pack p -> (bf16 hi<<16 | bf16 lo) via truncation split: hi = trunc16(p) (1 AND),
// lo = bf16(p - hi). hi+lo == p to ~2^-17; cheaper than RNE round-trip (4 ops vs 6).
__device__ __forceinline__ unsigned pk2(float p) {
    unsigned pu = __builtin_bit_cast(unsigned, p);
    unsigned hb = pu & 0xffff0000u;
    float l = p - __builtin_bit_cast(float, hb);
    __bf16 lb = (__bf16)l;
    return hb | (unsigned)__builtin_bit_cast(unsigned short, lb);
}
__device__ __forceinline__ float upk_hi(unsigned u) { return __builtin_bit_cast(float, u & 0xffff0000u); }
__device__ __forceinline__ float upk_lo(unsigned u) { return __builtin_bit_cast(float, u << 16); }

__device__ __forceinline__ bf16x8 sel_frag(uint4 a, uint4 b, unsigned s) {
    uint4 r;
    r.x = __builtin_amdgcn_perm(a.y, a.x, s);
    r.y = __builtin_amdgcn_perm(a.w, a.z, s);
    r.z = __builtin_amdgcn_perm(b.y, b.x, s);
    r.w = __builtin_amdgcn_perm(b.w, b.z, s);
    return __builtin_bit_cast(bf16x8, r);
}

__device__ __forceinline__ void split8(const float* __restrict__ src,
    __bf16* __restrict__ hi, __bf16* __restrict__ lo, size_t i)
{
    float4 a = *(const float4*)(src + i);
    float4 b = *(const float4*)(src + i + 4);
    float v[8] = {a.x, a.y, a.z, a.w, b.x, b.y, b.z, b.w};
    bf16x8 h, l;
    #pragma unroll
    for (int j = 0; j < 8; ++j) {
        __bf16 x = (__bf16)v[j];
        h[j] = x;
        l[j] = (__bf16)(v[j] - (float)x);
    }
    *(bf16x8*)(hi + i) = h;
    *(bf16x8*)(lo + i) = l;
}

// ---------------- all fp32->bf16 hi/lo splits in ONE launch ----------------
// blocks 0..12287: q/k/v (4096 each); 12288..14335: Wq/Wk/Wv/Wo (512 each)
__global__ __launch_bounds__(256) void splitAll(
    const float* __restrict__ q, const float* __restrict__ k, const float* __restrict__ v,
    const float* __restrict__ wq, const float* __restrict__ wk,
    const float* __restrict__ wv, const float* __restrict__ wo,
    __bf16* __restrict__ xqh, __bf16* __restrict__ xql,
    __bf16* __restrict__ xkh, __bf16* __restrict__ xkl,
    __bf16* __restrict__ xvh, __bf16* __restrict__ xvl,
    __bf16* __restrict__ wqh, __bf16* __restrict__ wql,
    __bf16* __restrict__ wkh, __bf16* __restrict__ wkl,
    __bf16* __restrict__ wvh, __bf16* __restrict__ wvl,
    __bf16* __restrict__ woh, __bf16* __restrict__ wol)
{
    const int id = blockIdx.x;
    const float* src;
    __bf16 *hi, *lo;
    size_t base;
    if (id < 12288) {
        int z = id >> 12, loc = id & 4095;
        src = z == 0 ? q : z == 1 ? k : v;
        hi  = z == 0 ? xqh : z == 1 ? xkh : xvh;
        lo  = z == 0 ? xql : z == 1 ? xkl : xvl;
        base = (size_t)loc * 2048;
    } else {
        int w = (id - 12288) >> 9, loc = (id - 12288) & 511;
        src = w == 0 ? wq : w == 1 ? wk : w == 2 ? wv : wo;
        hi  = w == 0 ? wqh : w == 1 ? wkh : w == 2 ? wvh : woh;
        lo  = w == 0 ? wql : w == 1 ? wkl : w == 2 ? wvl : wol;
        base = (size_t)loc * 2048;
    }
    split8(src, hi, lo, base + threadIdx.x * 8);
}

// ---------------- batched QKV projection GEMM (z selects tensor) ----------------
// Outputs written in FRAGMENT-TILED layout per (b,h) head (see attnF).
__global__ __launch_bounds__(256) void gemmQKV(
    const __bf16* __restrict__ xqh, const __bf16* __restrict__ xql,
    const __bf16* __restrict__ xkh, const __bf16* __restrict__ xkl,
    const __bf16* __restrict__ xvh, const __bf16* __restrict__ xvl,
    const __bf16* __restrict__ wqh, const __bf16* __restrict__ wql,
    const __bf16* __restrict__ wkh, const __bf16* __restrict__ wkl,
    const __bf16* __restrict__ wvh, const __bf16* __restrict__ wvl,
    __bf16* __restrict__ Qh, __bf16* __restrict__ Ql,
    __bf16* __restrict__ Kh, __bf16* __restrict__ Kl,
    __bf16* __restrict__ Vh, __bf16* __restrict__ Vl)
{
    const int z = blockIdx.z;
    const __bf16* Ah = z == 0 ? xqh : z == 1 ? xkh : xvh;
    const __bf16* Al = z == 0 ? xql : z == 1 ? xkl : xvl;
    const __bf16* Bh = z == 0 ? wqh : z == 1 ? wkh : wvh;
    const __bf16* Bl = z == 0 ? wql : z == 1 ? wkl : wvl;
    __bf16* Ch = z == 0 ? Qh : z == 1 ? Kh : Vh;
    __bf16* Cl = z == 0 ? Ql : z == 1 ? Kl : Vl;
    const int K = EE;

    __shared__ __bf16 sA[2][128 * 32];
    __shared__ __bf16 sB[2][128 * 32];
    const int tid = threadIdx.x, wave = tid >> 6, lane = tid & 63;
    const int quad = lane >> 4, l15 = lane & 15;
    const int m0 = blockIdx.y * 128, n0 = blockIdx.x * 128;
    const int wm = (wave >> 1) * 64, wn = (wave & 1) * 64;
    const int srow = lane >> 2, scol = (lane & 3) * 8;

    f32x4 acc[4][4];
    #pragma unroll
    for (int i = 0; i < 4; ++i)
        #pragma unroll
        for (int j = 0; j < 4; ++j)
            acc[i][j] = (f32x4){0.f, 0.f, 0.f, 0.f};

    for (int k0 = 0; k0 < K; k0 += 32) {
        __syncthreads();
        #pragma unroll
        for (int i = 0; i < 2; ++i) {
            int c = wave * 2 + i;
            size_t ga = (size_t)(m0 + c * 16 + srow) * K + k0 + scol;
            size_t gb = (size_t)(n0 + c * 16 + srow) * K + k0 + scol;
            gll16(Ah + ga, &sA[0][c * 512]);
            gll16(Al + ga, &sA[1][c * 512]);
            gll16(Bh + gb, &sB[0][c * 512]);
            gll16(Bl + gb, &sB[1][c * 512]);
        }
        __syncthreads();
        bf16x8 fAh[4], fAl[4], fBh[4], fBl[4];
        #pragma unroll
        for (int mb = 0; mb < 4; ++mb) {
            int r = (wm + mb * 16 + l15) * 32 + quad * 8;
            fAh[mb] = *(const bf16x8*)&sA[0][r];
            fAl[mb] = *(const bf16x8*)&sA[1][r];
        }
        #pragma unroll
        for (int nb = 0; nb < 4; ++nb) {
            int r = (wn + nb * 16 + l15) * 32 + quad * 8;
            fBh[nb] = *(const bf16x8*)&sB[0][r];
            fBl[nb] = *(const bf16x8*)&sB[1][r];
        }
        #pragma unroll
        for (int mb = 0; mb < 4; ++mb)
            #pragma unroll
            for (int nb = 0; nb < 4; ++nb)
                acc[mb][nb] = mm3(fAh[mb], fAl[mb], fBh[nb], fBl[nb], acc[mb][nb]);
    }

    #pragma unroll
    for (int mb = 0; mb < 4; ++mb)
        #pragma unroll
        for (int nb = 0; nb < 4; ++nb)
            #pragma unroll
            for (int r = 0; r < 4; ++r) {
                int m = m0 + wm + mb * 16 + quad * 4 + r;
                int n = n0 + wn + nb * 16 + l15;
                float v = acc[mb][nb][r];
                int b = m >> 11, t = m & (TS - 1);
                int h = n >> 6,  d = n & (DD - 1);
                __bf16 hi = (__bf16)v;
                __bf16 lo = (__bf16)(v - (float)hi);
                size_t hbase = ((size_t)b * HH + h) * TS * DD;
                size_t off;
                if (z == 2)
                    off = hbase + (size_t)(((d >> 4) * 64 + (t >> 5)) * 512
                          + (((t >> 3) & 3) * 16 + (d & 15)) * 8 + (t & 7));
                else
                    off = hbase + (size_t)(((t >> 4) * 2 + (d >> 5)) * 512
                          + (((d >> 3) & 3) * 16 + (t & 15)) * 8 + (d & 7));
                Ch[off] = hi;
                Cl[off] = lo;
            }
}

// ---------------- two-pass MFMA flash attention, fragment-tiled Q/K/V ----------
// All Q/K/V fragment loads are contiguous 1KB wave-loads (tile*512 + lane*8).
// NOTE: plain __launch_bounds__(256) — do NOT add a min-waves clamp (round-3 spill).
__global__ __launch_bounds__(256) void attnF(
    const __bf16* __restrict__ Qh, const __bf16* __restrict__ Ql,
    const __bf16* __restrict__ Kh, const __bf16* __restrict__ Kl,
    const __bf16* __restrict__ VhT, const __bf16* __restrict__ VlT,
    __bf16* __restrict__ avh, __bf16* __restrict__ avl,
    float* __restrict__ out1, _Float16* __restrict__ pp)
{
    __shared__ unsigned Pt[4][32][68];
    const int tid = threadIdx.x, wave = tid >> 6, lane = tid & 63;
    const int quad = lane >> 4, l15 = lane & 15;
    const int linear = blockIdx.x + 64 * blockIdx.y + 256 * blockIdx.z;
    const int bg = (linear & 7) + 8 * (linear >> 9);
    const int tt = (linear >> 3) & 63;
    const int b = bg & 3, g = bg >> 2;
    const int t0 = tt * 32;
    const int h = g * 4 + wave;
    const size_t hoff = (size_t)(b * HH + h);
    const __bf16* qhp = Qh + hoff * TS * DD;
    const __bf16* qlp = Ql + hoff * TS * DD;
    const __bf16* khp = Kh + hoff * TS * DD;
    const __bf16* klp = Kl + hoff * TS * DD;
    const __bf16* vhp = VhT + hoff * DD * TS;
    const __bf16* vlp = VlT + hoff * DD * TS;
    _Float16* myp = pp + (size_t)(g - 1) * ((size_t)BB * TS * TS);

    const int loff = (quad * 16 + l15) * 8;   // lane offset within a 512-elem tile

    bf16x8 fqh[2][2], fql[2][2];
    #pragma unroll
    for (int tb = 0; tb < 2; ++tb)
        #pragma unroll
        for (int ks = 0; ks < 2; ++ks) {
            size_t o = (size_t)((((t0 >> 4) + tb) * 2 + ks) * 512 + loff);
            fqh[tb][ks] = *(const bf16x8*)(qhp + o);
            fql[tb][ks] = *(const bf16x8*)(qlp + o);
        }

    // ---- pass A: l = sum exp(s - MS); no barriers, no LDS ----
    float lacc[2][4];
    #pragma unroll
    for (int tb = 0; tb < 2; ++tb)
        #pragma unroll
        for (int r = 0; r < 4; ++r) lacc[tb][r] = 0.f;

    for (int st = 0; st < 32; ++st) {
        bf16x8 kh[4][2], kl[4][2];
        #pragma unroll
        for (int sb = 0; sb < 4; ++sb) {
            const int kt = ((st * 4 + sb) * 2) * 512 + loff;
            kh[sb][0] = *(const bf16x8*)(khp + kt);
            kh[sb][1] = *(const bf16x8*)(khp + kt + 512);
            kl[sb][0] = *(const bf16x8*)(klp + kt);
            kl[sb][1] = *(const bf16x8*)(klp + kt + 512);
        }
        #pragma unroll
        for (int sb = 0; sb < 4; ++sb)
            #pragma unroll
            for (int tb = 0; tb < 2; ++tb) {
                f32x4 c = (f32x4){0.f, 0.f, 0.f, 0.f};
                c = mm3(fqh[tb][0], fql[tb][0], kh[sb][0], kl[sb][0], c);
                c = mm3(fqh[tb][1], fql[tb][1], kh[sb][1], kl[sb][1], c);
                #pragma unroll
                for (int r = 0; r < 4; ++r)
                    lacc[tb][r] += pexp(c[r]);
            }
    }
    float rf[2][4];
    #pragma unroll
    for (int tb = 0; tb < 2; ++tb)
        #pragma unroll
        for (int r = 0; r < 4; ++r) {
            float v = lacc[tb][r];
            v += __shfl_xor(v, 1);
            v += __shfl_xor(v, 2);
            v += __shfl_xor(v, 4);
            v += __shfl_xor(v, 8);
            rf[tb][r] = 1.0f / v;
        }

    // ---- pass B: exact probs (identical score recompute), PV, out1 ----
    f32x4 oacc[2][4];
    #pragma unroll
    for (int tb = 0; tb < 2; ++tb)
        #pragma unroll
        for (int db = 0; db < 4; ++db) oacc[tb][db] = (f32x4){0.f, 0.f, 0.f, 0.f};

    for (int st = 0; st < 32; ++st) {
        bf16x8 kh[4][2], kl[4][2];
        #pragma unroll
        for (int sb = 0; sb < 4; ++sb) {
            const int kt = ((st * 4 + sb) * 2) * 512 + loff;
            kh[sb][0] = *(const bf16x8*)(khp + kt);
            kh[sb][1] = *(const bf16x8*)(khp + kt + 512);
            kl[sb][0] = *(const bf16x8*)(klp + kt);
            kl[sb][1] = *(const bf16x8*)(klp + kt + 512);
        }
        #pragma unroll
        for (int sb = 0; sb < 4; ++sb)
            #pragma unroll
            for (int tb = 0; tb < 2; ++tb) {
                f32x4 c = (f32x4){0.f, 0.f, 0.f, 0.f};
                c = mm3(fqh[tb][0], fql[tb][0], kh[sb][0], kl[sb][0], c);
                c = mm3(fqh[tb][1], fql[tb][1], kh[sb][1], kl[sb][1], c);
                #pragma unroll
                for (int r = 0; r < 4; ++r) {
                    float p = pexp(c[r]) * rf[tb][r];
                    Pt[wave][tb * 16 + quad * 4 + r][sb * 16 + l15] = pk2(p);
                }
            }
        LBAR();

        // V fragments (tiled) — contiguous 1KB wave-loads
        bf16x8 vh[4][2], vl[4][2];
        #pragma unroll
        for (int db = 0; db < 4; ++db) {
            const int vt = (db * 64 + st * 2) * 512 + loff;
            vh[db][0] = *(const bf16x8*)(vhp + vt);
            vh[db][1] = *(const bf16x8*)(vhp + vt + 512);
            vl[db][0] = *(const bf16x8*)(vlp + vt);
            vl[db][1] = *(const bf16x8*)(vlp + vt + 512);
        }

        bf16x8 fph[2][2], fpl[2][2];
        #pragma unroll
        for (int tb = 0; tb < 2; ++tb)
            #pragma unroll
            for (int ks = 0; ks < 2; ++ks) {
                const unsigned* ppt = &Pt[wave][tb * 16 + l15][ks * 32 + quad * 8];
                uint4 a = *(const uint4*)ppt;
                uint4 bq = *(const uint4*)(ppt + 4);
                fph[tb][ks] = sel_frag(a, bq, 0x07060302u);
                fpl[tb][ks] = sel_frag(a, bq, 0x05040100u);
            }

        // out1 partial: cross-wave (4-head) sum -> one plain vector store per thread
        {
            int row = tid >> 3, s8 = (tid & 7) * 8;
            float vs[8] = {0.f, 0.f, 0.f, 0.f, 0.f, 0.f, 0.f, 0.f};
#ifdef HAS_DOT2
            const bf16x2 one2 = {(__bf16)1.0f, (__bf16)1.0f};
#endif
            #pragma unroll
            for (int w = 0; w < 4; ++w) {
                const unsigned* pw = &Pt[w][row][s8];
                uint4 a = *(const uint4*)pw;
                uint4 bq = *(const uint4*)(pw + 4);
                unsigned uu[8] = {a.x, a.y, a.z, a.w, bq.x, bq.y, bq.z, bq.w};
                #pragma unroll
                for (int j = 0; j < 8; ++j) {
#ifdef HAS_DOT2
                    vs[j] = __builtin_amdgcn_fdot2_f32_bf16(
                        __builtin_bit_cast(bf16x2, uu[j]), one2, vs[j], false);
#else
                    vs[j] += upk_hi(uu[j]) + upk_lo(uu[j]);
#endif
                }
            }
            size_t off = ((size_t)b * TS + t0 + row) * TS + st * 64 + s8;
            if (g == 0) {
                float4 o0, o1v;
                o0.x = vs[0] * 0.0625f; o0.y = vs[1] * 0.0625f;
                o0.z = vs[2] * 0.0625f; o0.w = vs[3] * 0.0625f;
                o1v.x = vs[4] * 0.0625f; o1v.y = vs[5] * 0.0625f;
                o1v.z = vs[6] * 0.0625f; o1v.w = vs[7] * 0.0625f;
                *(float4*)(out1 + off) = o0;
                *(float4*)(out1 + off + 4) = o1v;
            } else {
                f16x8 hv;
                #pragma unroll
                for (int j = 0; j < 8; ++j)
                    hv[j] = (_Float16)(vs[j] * 0.0625f);
                *(f16x8*)(myp + off) = hv;
            }
        }

        #pragma unroll
        for (int db = 0; db < 4; ++db)
            #pragma unroll
            for (int tb = 0; tb < 2; ++tb) {
                f32x4 o = oacc[tb][db];
                o = mm3(fph[tb][0], fpl[tb][0], vh[db][0], vl[db][0], o);
                o = mm3(fph[tb][1], fpl[tb][1], vh[db][1], vl[db][1], o);
                oacc[tb][db] = o;
            }
        LBAR();
    }

    // epilogue: avec as hi/lo bf16 [B*T, H*D]
    #pragma unroll
    for (int tb = 0; tb < 2; ++tb)
        #pragma unroll
        for (int db = 0; db < 4; ++db)
            #pragma unroll
            for (int r = 0; r < 4; ++r) {
                int row = t0 + tb * 16 + quad * 4 + r;
                int col = h * 64 + db * 16 + l15;
                float v = oacc[tb][db][r];
                __bf16 hi = (__bf16)v;
                size_t o = ((size_t)b * TS + row) * EE + col;
                avh[o] = hi;
                avl[o] = (__bf16)(v - (float)hi);
            }
}

// ---------------- output GEMM fused with out1 reduce ----------------
// blockIdx.x < 8: C[M,N] = A*B^T tile (out0 path).
// blockIdx.x >= 8: out1 += p1+p2+p3 streaming chunk (redk path) — overlaps the
// GEMM's compute-bound blocks with memory-bound reduce work in one dispatch.
__global__ __launch_bounds__(256) void gemmO(
    const __bf16* __restrict__ Ah, const __bf16* __restrict__ Al,
    const __bf16* __restrict__ Bh, const __bf16* __restrict__ Bl,
    float* __restrict__ Cf, float* __restrict__ out1,
    const _Float16* __restrict__ pp, int M, int N, int K)
{
    __shared__ __bf16 sA[2][128 * 32];
    __shared__ __bf16 sB[2][128 * 32];
    const int tid = threadIdx.x;

    if (blockIdx.x >= 8) {
        // ---- redk path ----
        const size_t P = (size_t)BB * TS * TS;
        size_t r = (size_t)(blockIdx.x - 8) + 128 * blockIdx.y;
        size_t i = (r * 256 + tid) * 8;
        float4 a = *(const float4*)(out1 + i);
        float4 c = *(const float4*)(out1 + i + 4);
        f16x8 q1 = *(const f16x8*)(pp + i);
        f16x8 q2 = *(const f16x8*)(pp + P + i);
        f16x8 q3 = *(const f16x8*)(pp + 2 * P + i);
        a.x += (float)q1[0] + (float)q2[0] + (float)q3[0];
        a.y += (float)q1[1] + (float)q2[1] + (float)q3[1];
        a.z += (float)q1[2] + (float)q2[2] + (float)q3[2];
        a.w += (float)q1[3] + (float)q2[3] + (float)q3[3];
        c.x += (float)q1[4] + (float)q2[4] + (float)q3[4];
        c.y += (float)q1[5] + (float)q2[5] + (float)q3[5];
        c.z += (float)q1[6] + (float)q2[6] + (float)q3[6];
        c.w += (float)q1[7] + (float)q2[7] + (float)q3[7];
        *(float4*)(out1 + i) = a;
        *(float4*)(out1 + i + 4) = c;
        return;
    }

    // ---- GEMM path ----
    const int wave = tid >> 6, lane = tid & 63;
    const int quad = lane >> 4, l15 = lane & 15;
    const int m0 = blockIdx.y * 128, n0 = blockIdx.x * 128;
    const int wm = (wave >> 1) * 64, wn = (wave & 1) * 64;
    const int srow = lane >> 2, scol = (lane & 3) * 8;

    f32x4 acc[4][4];
    #pragma unroll
    for (int i = 0; i < 4; ++i)
        #pragma unroll
        for (int j = 0; j < 4; ++j)
            acc[i][j] = (f32x4){0.f, 0.f, 0.f, 0.f};

    for (int k0 = 0; k0 < K; k0 += 32) {
        __syncthreads();
        #pragma unroll
        for (int i = 0; i < 2; ++i) {
            int c = wave * 2 + i;
            size_t ga = (size_t)(m0 + c * 16 + srow) * K + k0 + scol;
            size_t gb = (size_t)(n0 + c * 16 + srow) * K + k0 + scol;
            gll16(Ah + ga, &sA[0][c * 512]);
            gll16(Al + ga, &sA[1][c * 512]);
            gll16(Bh + gb, &sB[0][c * 512]);
            gll16(Bl + gb, &sB[1][c * 512]);
        }
        __syncthreads();
        bf16x8 fAh[4], fAl[4], fBh[4], fBl[4];
        #pragma unroll
        for (int mb = 0; mb < 4; ++mb) {
            int r = (wm + mb * 16 + l15) * 32 + quad * 8;
            fAh[mb] = *(const bf16x8*)&sA[0][r];
            fAl[mb] = *(const bf16x8*)&sA[1][r];
        }
        #pragma unroll
        for (int nb = 0; nb < 4; ++nb) {
            int r = (wn + nb * 16 + l15) * 32 + quad * 8;
            fBh[nb] = *(const bf16x8*)&sB[0][r];
            fBl[nb] = *(const bf16x8*)&sB[1][r];
        }
        #pragma unroll
        for (int mb = 0; mb < 4; ++mb)
            #pragma unroll
            for (int nb = 0; nb < 4; ++nb)
                acc[mb][nb] = mm3(fAh[mb], fAl[mb], fBh[nb], fBl[nb], acc[mb][nb]);
    }

    #pragma unroll
    for (int mb = 0; mb < 4; ++mb)
        #pragma unroll
        for (int nb = 0; nb < 4; ++nb)
            #pragma unroll
            for (int r = 0; r < 4; ++r) {
                int m = m0 + wm + mb * 16 + quad * 4 + r;
                int n = n0 + wn + nb * 16 + l15;
                Cf[(size_t)m * N + n] = acc[mb][nb][r];
            }
}

extern "C" void kernel_launch(void* const* d_in, const int* in_sizes, int n_in,
                              void* d_out, int out_size, void* d_ws, size_t ws_size,
                              hipStream_t stream)
{
    const float* query = (const float*)d_in[0];
    const float* key_  = (const float*)d_in[1];
    const float* value = (const float*)d_in[2];
    const float* Wq    = (const float*)d_in[3];
    const float* Wk    = (const float*)d_in[4];
    const float* Wv    = (const float*)d_in[5];
    const float* Wo    = (const float*)d_in[6];

    float* out0 = (float*)d_out;                 // [B,T,E]
    float* out1 = out0 + (size_t)BB * TS * EE;   // [B,T,S]

    char* base = (char*)d_ws;
    const size_t U = 16777216;
    __bf16* xqh = (__bf16*)(base + 0 * U);
    __bf16* xql = (__bf16*)(base + 1 * U);
    __bf16* xkh = (__bf16*)(base + 2 * U);
    __bf16* xkl = (__bf16*)(base + 3 * U);
    __bf16* xvh = (__bf16*)(base + 4 * U);
    __bf16* xvl = (__bf16*)(base + 5 * U);
    __bf16* Qhp = (__bf16*)(base + 6 * U);
    __bf16* Qlp = (__bf16*)(base + 7 * U);
    __bf16* Khp = (__bf16*)(base + 8 * U);
    __bf16* Klp = (__bf16*)(base + 9 * U);
    __bf16* VhT = (__bf16*)(base + 10 * U);
    __bf16* VlT = (__bf16*)(base + 11 * U);
    __bf16* avh = (__bf16*)(base + 12 * U);
    __bf16* avl = (__bf16*)(base + 13 * U);
    __bf16* wqh = (__bf16*)(base + 14 * U);
    __bf16* wql = wqh + 1048576;
    __bf16* wkh = wql + 1048576;
    __bf16* wkl = wkh + 1048576;
    __bf16* wvh = wkl + 1048576;
    __bf16* wvl = wvh + 1048576;
    __bf16* woh = wvl + 1048576;
    __bf16* wol = woh + 1048576;
    // fp16 out1 partials for g=1..3 alias the xq/xk/xv splits (dead after gemmQKV)
    _Float16* pp = (_Float16*)(base + 0 * U);

    splitAll<<<14336, 256, 0, stream>>>(query, key_, value, Wq, Wk, Wv, Wo,
                                        xqh, xql, xkh, xkl, xvh, xvl,
                                        wqh, wql, wkh, wkl, wvh, wvl, woh, wol);

    gemmQKV<<<dim3(8, 64, 3), 256, 0, stream>>>(xqh, xql, xkh, xkl, xvh, xvl,
                                                wqh, wql, wkh, wkl, wvh, wvl,
                                                Qhp, Qlp, Khp, Klp, VhT, VlT);

    attnF<<<dim3(64, 4, 4), 256, 0, stream>>>(Qhp, Qlp, Khp, Klp, VhT, VlT,
                                              avh, avl, out1, pp);

    gemmO<<<dim3(136, 64), 256, 0, stream>>>(avh, avl, woh, wol, out0, out1, pp,
                                             8192, 1024, 1024);
}